// Round 1
// baseline (845.567 us; speedup 1.0000x reference)
//
#include <hip/hip_runtime.h>

#define BATCH 32
#define NPTS  1024
#define NFEAT 256
#define NPROP 256
#define NSAMP 16

// flat output offsets (floats), in reference tuple order
#define O_OBJ    0
#define O_CENTER 16384
#define O_HS     40960
#define O_HRN    139264
#define O_HR     237568
#define O_SS     335872
#define O_SRN    483328
#define O_SR     925696
#define O_SEM    1368064
#define O_NX     1515520
#define O_INDS   1540096

#define XST 264   // xb row stride (words): 256 feat + 3 gxyz + pad, 16B-aligned rows
#define YST 132   // layer buffer row stride

// ---------------------------------------------------------------------------
// Kernel 1: FPS (bit-exact fp32, first-max argmax) + ball query, one block/batch
// ---------------------------------------------------------------------------
__global__ __launch_bounds__(256) void fps_bq_kernel(
    const float* __restrict__ xyz,
    float* __restrict__ o_nx,     // new_xyz output region
    float* __restrict__ o_inds,   // inds output region (as float)
    int*   __restrict__ ws_idx)   // [B*P*NS] neighbor indices
{
  __shared__ float sx[NPTS], sy[NPTS], sz[NPTS];
  __shared__ float rv[256];
  __shared__ int   ri[256];
  __shared__ int   sInd[NPROP];
  __shared__ int   sLast;

  const int b = blockIdx.x;
  const int t = threadIdx.x;
  const float* xb = xyz + b * NPTS * 3;
  for (int k = t; k < NPTS; k += 256) {
    sx[k] = xb[k*3+0];
    sy[k] = xb[k*3+1];
    sz[k] = xb[k*3+2];
  }
  if (t == 0) sInd[0] = 0;
  __syncthreads();

  float px[4], py[4], pz[4], dd[4];
#pragma unroll
  for (int j = 0; j < 4; ++j) {
    int k = t + 256*j;
    px[j] = sx[k]; py[j] = sy[k]; pz[j] = sz[k];
    dd[j] = 1e10f;
  }

  int last = 0;
  for (int it = 1; it < NPROP; ++it) {
    float lx = sx[last], ly = sy[last], lz = sz[last];
    float bv = -1.0f; int bi = 0;
#pragma unroll
    for (int j = 0; j < 4; ++j) {
      // IEEE, no FMA contraction: must match numpy sub/square/sum exactly
      float dx = __fsub_rn(px[j], lx);
      float dy = __fsub_rn(py[j], ly);
      float dz = __fsub_rn(pz[j], lz);
      float d  = __fadd_rn(__fadd_rn(__fmul_rn(dx,dx), __fmul_rn(dy,dy)), __fmul_rn(dz,dz));
      d = fminf(dd[j], d);
      dd[j] = d;
      if (d > bv) { bv = d; bi = t + 256*j; }   // ascending idx: strict > keeps lowest
    }
    rv[t] = bv; ri[t] = bi;
    __syncthreads();
    if (t < 64) {
      float v = rv[t]; int i = ri[t];
#pragma unroll
      for (int q = 1; q < 4; ++q) {
        float v2 = rv[t + 64*q]; int i2 = ri[t + 64*q];
        if (v2 > v || (v2 == v && i2 < i)) { v = v2; i = i2; }
      }
#pragma unroll
      for (int m = 32; m >= 1; m >>= 1) {
        float v2 = __shfl_xor(v, m);
        int   i2 = __shfl_xor(i, m);
        if (v2 > v || (v2 == v && i2 < i)) { v = v2; i = i2; }
      }
      if (t == 0) { sLast = i; sInd[it] = i; }
    }
    __syncthreads();
    last = sLast;
  }

  // write inds + new_xyz, then ball query (scan order == sorted candidate order)
  {
    int ind = sInd[t];
    o_inds[b*NPROP + t] = (float)ind;
    float qx = sx[ind], qy = sy[ind], qz = sz[ind];
    float* nx = o_nx + (b*NPROP + t)*3;
    nx[0] = qx; nx[1] = qy; nx[2] = qz;

    int cnt = 0;
    int first = NPTS - 1;   // reference: no hit -> min(K, K-1)
    int base = (b*NPROP + t)*NSAMP;
    for (int k = 0; k < NPTS && cnt < NSAMP; ++k) {
      float dx = __fsub_rn(qx, sx[k]);
      float dy = __fsub_rn(qy, sy[k]);
      float dz = __fsub_rn(qz, sz[k]);
      float d2 = __fadd_rn(__fadd_rn(__fmul_rn(dx,dx), __fmul_rn(dy,dy)), __fmul_rn(dz,dz));
      if (d2 < 0.09f) {
        if (cnt == 0) first = k;
        ws_idx[base + cnt] = k;
        ++cnt;
      }
    }
    for (int j = cnt; j < NSAMP; ++j) ws_idx[base + j] = first;
  }
}

// ---------------------------------------------------------------------------
// Kernel 2: grouped MLP (259->128->128->128) + maxpool + FC head, one block/(b,p)
// ---------------------------------------------------------------------------
#define FMA16(xv, wv0, wv1, wv2, wv3, a) do { \
  a[0] = fmaf(xv.x, wv0.x, a[0]); a[1] = fmaf(xv.x, wv0.y, a[1]); \
  a[2] = fmaf(xv.x, wv0.z, a[2]); a[3] = fmaf(xv.x, wv0.w, a[3]); \
  a[0] = fmaf(xv.y, wv1.x, a[0]); a[1] = fmaf(xv.y, wv1.y, a[1]); \
  a[2] = fmaf(xv.y, wv1.z, a[2]); a[3] = fmaf(xv.y, wv1.w, a[3]); \
  a[0] = fmaf(xv.z, wv2.x, a[0]); a[1] = fmaf(xv.z, wv2.y, a[1]); \
  a[2] = fmaf(xv.z, wv2.z, a[2]); a[3] = fmaf(xv.z, wv2.w, a[3]); \
  a[0] = fmaf(xv.w, wv3.x, a[0]); a[1] = fmaf(xv.w, wv3.y, a[1]); \
  a[2] = fmaf(xv.w, wv3.z, a[2]); a[3] = fmaf(xv.w, wv3.w, a[3]); \
} while (0)

__device__ __forceinline__ void gemm_tile_128(
    const float* __restrict__ w, const float* src, int chg, float acc[4][4])
{
  const float4* wv4 = (const float4*)w;
  for (int c4 = 0; c4 < 32; ++c4) {
    float4 wv0 = wv4[(c4*4+0)*32 + chg];
    float4 wv1 = wv4[(c4*4+1)*32 + chg];
    float4 wv2 = wv4[(c4*4+2)*32 + chg];
    float4 wv3 = wv4[(c4*4+3)*32 + chg];
#pragma unroll
    for (int si = 0; si < 4; ++si) {
      float4 xv = *(const float4*)(src + si*YST + c4*4);
      FMA16(xv, wv0, wv1, wv2, wv3, acc[si]);
    }
  }
}

__global__ __launch_bounds__(128) void mlp_head_kernel(
    const float* __restrict__ xyz,  const float* __restrict__ feats,
    const float* __restrict__ msize,
    const float* __restrict__ w0,  const float* __restrict__ b0,
    const float* __restrict__ g0,  const float* __restrict__ be0,
    const float* __restrict__ w1,  const float* __restrict__ b1,
    const float* __restrict__ g1,  const float* __restrict__ be1,
    const float* __restrict__ w2,  const float* __restrict__ b2,
    const float* __restrict__ g2,  const float* __restrict__ be2,
    const float* __restrict__ wf1, const float* __restrict__ bf1,
    const float* __restrict__ gf1, const float* __restrict__ bef1,
    const float* __restrict__ wf2, const float* __restrict__ bf2,
    const float* __restrict__ gf2, const float* __restrict__ bef2,
    const float* __restrict__ w3,  const float* __restrict__ b3,
    const int* __restrict__ ws_idx,
    float* __restrict__ out)
{
  __shared__ float xb[16*XST];   // input tile; later reused as layer-1 output (zb)
  __shared__ float yb[16*YST];   // layer-0 output; later part/sfeat/sn1/sn2
  __shared__ int   sIdx[16];
  __shared__ float sq[3];

  const int t  = threadIdx.x;
  const int bp = blockIdx.x;
  const int b  = bp >> 8;

  if (t < 16) sIdx[t] = ws_idx[bp*16 + t];
  if (t >= 16 && t < 19) sq[t-16] = out[O_NX + bp*3 + (t-16)];
  __syncthreads();

  // stage gathered features: xb[s][0..255]
  {
    const int half = t >> 6;
    const int lane = t & 63;
#pragma unroll
    for (int s2 = 0; s2 < 8; ++s2) {
      int s = s2*2 + half;
      const float4* src = (const float4*)(feats + (size_t)(b*NPTS + sIdx[s]) * NFEAT);
      *((float4*)(xb + s*XST) + lane) = src[lane];
    }
  }
  // gxyz at xb[s][256..258]  (w rows 0..2)
  if (t < 48) {
    int s = t / 3, j = t - s*3;
    float v = xyz[(b*NPTS + sIdx[s])*3 + j];
    xb[s*XST + 256 + j] = (v - sq[j]) / 0.3f;
  }
  __syncthreads();

  const int sgrp = t >> 5;      // 0..3 : owns s rows sgrp*4..+3
  const int chg  = t & 31;      // 0..31: owns channels chg*4..+3
  const int ch0  = chg * 4;

  float acc[4][4];
#pragma unroll
  for (int i = 0; i < 4; ++i)
#pragma unroll
    for (int j = 0; j < 4; ++j) acc[i][j] = 0.0f;

  // ---- layer 0: 259 -> 128 (feat channels use w rows c+3; gxyz uses rows 0..2)
  {
    const float4* wv4 = (const float4*)w0;
    const float* xr = xb + sgrp*4*XST;
    for (int c4 = 0; c4 < 64; ++c4) {
      float4 wv0 = wv4[(c4*4+3)*32 + chg];
      float4 wv1 = wv4[(c4*4+4)*32 + chg];
      float4 wv2 = wv4[(c4*4+5)*32 + chg];
      float4 wv3 = wv4[(c4*4+6)*32 + chg];
#pragma unroll
      for (int si = 0; si < 4; ++si) {
        float4 xv = *(const float4*)(xr + si*XST + c4*4);
        FMA16(xv, wv0, wv1, wv2, wv3, acc[si]);
      }
    }
#pragma unroll
    for (int j = 0; j < 3; ++j) {
      float4 wv = wv4[j*32 + chg];
#pragma unroll
      for (int si = 0; si < 4; ++si) {
        float xv = xr[si*XST + 256 + j];
        acc[si][0] = fmaf(xv, wv.x, acc[si][0]);
        acc[si][1] = fmaf(xv, wv.y, acc[si][1]);
        acc[si][2] = fmaf(xv, wv.z, acc[si][2]);
        acc[si][3] = fmaf(xv, wv.w, acc[si][3]);
      }
    }
    float4 gg = *(const float4*)(g0 + ch0);
    float4 b4 = *(const float4*)(b0 + ch0);
    float4 e4 = *(const float4*)(be0 + ch0);
#pragma unroll
    for (int si = 0; si < 4; ++si) {
      float4 o;
      o.x = fmaxf(fmaf(gg.x, acc[si][0] + b4.x, e4.x), 0.0f);
      o.y = fmaxf(fmaf(gg.y, acc[si][1] + b4.y, e4.y), 0.0f);
      o.z = fmaxf(fmaf(gg.z, acc[si][2] + b4.z, e4.z), 0.0f);
      o.w = fmaxf(fmaf(gg.w, acc[si][3] + b4.w, e4.w), 0.0f);
      *(float4*)(yb + (sgrp*4+si)*YST + ch0) = o;
    }
  }
  __syncthreads();

  // ---- layer 1: 128 -> 128 (reads yb, writes zb = xb region)
  float* zb = xb;
  {
#pragma unroll
    for (int i = 0; i < 4; ++i)
#pragma unroll
      for (int j = 0; j < 4; ++j) acc[i][j] = 0.0f;
    gemm_tile_128(w1, yb + sgrp*4*YST, chg, acc);
    float4 gg = *(const float4*)(g1 + ch0);
    float4 b4 = *(const float4*)(b1 + ch0);
    float4 e4 = *(const float4*)(be1 + ch0);
#pragma unroll
    for (int si = 0; si < 4; ++si) {
      float4 o;
      o.x = fmaxf(fmaf(gg.x, acc[si][0] + b4.x, e4.x), 0.0f);
      o.y = fmaxf(fmaf(gg.y, acc[si][1] + b4.y, e4.y), 0.0f);
      o.z = fmaxf(fmaf(gg.z, acc[si][2] + b4.z, e4.z), 0.0f);
      o.w = fmaxf(fmaf(gg.w, acc[si][3] + b4.w, e4.w), 0.0f);
      *(float4*)(zb + (sgrp*4+si)*YST + ch0) = o;
    }
  }
  __syncthreads();

  // ---- layer 2: 128 -> 128, activation, per-thread max over its 4 s-rows
  {
#pragma unroll
    for (int i = 0; i < 4; ++i)
#pragma unroll
      for (int j = 0; j < 4; ++j) acc[i][j] = 0.0f;
    gemm_tile_128(w2, zb + sgrp*4*YST, chg, acc);
    float4 gg = *(const float4*)(g2 + ch0);
    float4 b4 = *(const float4*)(b2 + ch0);
    float4 e4 = *(const float4*)(be2 + ch0);
    float4 mx; mx.x = -1e30f; mx.y = -1e30f; mx.z = -1e30f; mx.w = -1e30f;
#pragma unroll
    for (int si = 0; si < 4; ++si) {
      mx.x = fmaxf(mx.x, fmaxf(fmaf(gg.x, acc[si][0] + b4.x, e4.x), 0.0f));
      mx.y = fmaxf(mx.y, fmaxf(fmaf(gg.y, acc[si][1] + b4.y, e4.y), 0.0f));
      mx.z = fmaxf(mx.z, fmaxf(fmaf(gg.z, acc[si][2] + b4.z, e4.z), 0.0f));
      mx.w = fmaxf(mx.w, fmaxf(fmaf(gg.w, acc[si][3] + b4.w, e4.w), 0.0f));
    }
    // part[sgrp][128] in yb[0..511]  (safe: all yb reads done before prior barrier)
    *(float4*)(yb + sgrp*128 + ch0) = mx;
  }
  __syncthreads();

  float* sfeat = yb + 512;
  {
    float f = yb[t];
    f = fmaxf(f, yb[128 + t]);
    f = fmaxf(f, yb[256 + t]);
    f = fmaxf(f, yb[384 + t]);
    sfeat[t] = f;
  }
  __syncthreads();

  // ---- FC1 (relu6)
  float* sn1 = yb + 640;
  {
    float a1 = 0.0f;
#pragma unroll
    for (int c4 = 0; c4 < 32; ++c4) {
      float4 fv = *(const float4*)(sfeat + c4*4);
      a1 = fmaf(fv.x, wf1[(c4*4+0)*128 + t], a1);
      a1 = fmaf(fv.y, wf1[(c4*4+1)*128 + t], a1);
      a1 = fmaf(fv.z, wf1[(c4*4+2)*128 + t], a1);
      a1 = fmaf(fv.w, wf1[(c4*4+3)*128 + t], a1);
    }
    float v = fminf(fmaxf(fmaf(gf1[t], a1 + bf1[t], bef1[t]), 0.0f), 6.0f);
    sn1[t] = v;
  }
  __syncthreads();

  // ---- FC2 (relu6)
  float* sn2 = yb + 768;
  {
    float a2 = 0.0f;
#pragma unroll
    for (int c4 = 0; c4 < 32; ++c4) {
      float4 fv = *(const float4*)(sn1 + c4*4);
      a2 = fmaf(fv.x, wf2[(c4*4+0)*128 + t], a2);
      a2 = fmaf(fv.y, wf2[(c4*4+1)*128 + t], a2);
      a2 = fmaf(fv.z, wf2[(c4*4+2)*128 + t], a2);
      a2 = fmaf(fv.w, wf2[(c4*4+3)*128 + t], a2);
    }
    float v = fminf(fmaxf(fmaf(gf2[t], a2 + bf2[t], bef2[t]), 0.0f), 6.0f);
    sn2[t] = v;
  }
  __syncthreads();

  // ---- FC3 (119 outputs) + scatter with per-head transforms
  if (t < 119) {
    float a3 = 0.0f;
#pragma unroll
    for (int c4 = 0; c4 < 32; ++c4) {
      float4 fv = *(const float4*)(sn2 + c4*4);
      a3 = fmaf(fv.x, w3[(c4*4+0)*119 + t], a3);
      a3 = fmaf(fv.y, w3[(c4*4+1)*119 + t], a3);
      a3 = fmaf(fv.z, w3[(c4*4+2)*119 + t], a3);
      a3 = fmaf(fv.w, w3[(c4*4+3)*119 + t], a3);
    }
    float v = a3 + b3[t];
    const float HRC = (float)(3.14159265359 / 12.0);
    if (t < 3) {
      out[O_CENTER + bp*3 + t] = sq[t] + v;
    } else if (t < 5) {
      out[O_OBJ + bp*2 + (t-3)] = v;
    } else if (t < 17) {
      out[O_HS + bp*12 + (t-5)] = v;
    } else if (t < 35) {
      out[O_SS + bp*18 + (t-17)] = v;
    } else if (t < 47) {
      int a = t - 35;
      out[O_HRN + bp*12 + a] = v;
      out[O_HR  + bp*12 + a] = v * HRC;
    } else if (t < 101) {
      int a = t - 47;
      out[O_SRN + bp*54 + a] = v;
      out[O_SR  + bp*54 + a] = v * msize[a];
    } else {
      int a = t - 101;
      out[O_SEM + bp*18 + a] = v;
    }
  }
}

// ---------------------------------------------------------------------------
extern "C" void kernel_launch(void* const* d_in, const int* in_sizes, int n_in,
                              void* d_out, int out_size, void* d_ws, size_t ws_size,
                              hipStream_t stream) {
  (void)in_sizes; (void)n_in; (void)out_size; (void)ws_size;
  const float* xyz   = (const float*)d_in[0];
  const float* feats = (const float*)d_in[1];
  const float* msize = (const float*)d_in[2];
  const float* w0  = (const float*)d_in[3];
  const float* b0  = (const float*)d_in[4];
  const float* g0  = (const float*)d_in[5];
  const float* be0 = (const float*)d_in[6];
  const float* w1  = (const float*)d_in[7];
  const float* b1  = (const float*)d_in[8];
  const float* g1  = (const float*)d_in[9];
  const float* be1 = (const float*)d_in[10];
  const float* w2  = (const float*)d_in[11];
  const float* b2  = (const float*)d_in[12];
  const float* g2  = (const float*)d_in[13];
  const float* be2 = (const float*)d_in[14];
  const float* wf1  = (const float*)d_in[15];
  const float* bf1  = (const float*)d_in[16];
  const float* gf1  = (const float*)d_in[17];
  const float* bef1 = (const float*)d_in[18];
  const float* wf2  = (const float*)d_in[19];
  const float* bf2  = (const float*)d_in[20];
  const float* gf2  = (const float*)d_in[21];
  const float* bef2 = (const float*)d_in[22];
  const float* w3 = (const float*)d_in[23];
  const float* b3 = (const float*)d_in[24];

  float* out = (float*)d_out;
  int* ws_idx = (int*)d_ws;   // B*P*NS ints = 512 KiB

  fps_bq_kernel<<<BATCH, 256, 0, stream>>>(xyz, out + O_NX, out + O_INDS, ws_idx);
  mlp_head_kernel<<<BATCH*NPROP, 128, 0, stream>>>(
      xyz, feats, msize,
      w0, b0, g0, be0, w1, b1, g1, be1, w2, b2, g2, be2,
      wf1, bf1, gf1, bef1, wf2, bf2, gf2, bef2, w3, b3,
      ws_idx, out);
}

// Round 2
// 660.719 us; speedup vs baseline: 1.2798x; 1.2798x over previous
//
#include <hip/hip_runtime.h>

#define BATCH 32
#define NPTS  1024
#define NFEAT 256
#define NPROP 256
#define NSAMP 16

// flat output offsets (floats), in reference tuple order
#define O_OBJ    0
#define O_CENTER 16384
#define O_HS     40960
#define O_HRN    139264
#define O_HR     237568
#define O_SS     335872
#define O_SRN    483328
#define O_SR     925696
#define O_SEM    1368064
#define O_NX     1515520
#define O_INDS   1540096

#define XST 264   // xb row stride (words): 256 feat + 3 gxyz + pad, 16B-aligned rows
#define YST 132   // layer buffer row stride

// ---------------------------------------------------------------------------
// Kernel 1: FPS — one wave (64 lanes) per batch, 16 points/lane in registers.
// Zero barriers on the 255-step serial path; argmax via shfl_xor butterfly.
// Bit-exact fp32 (no FMA contraction), first-max tie-break like jnp.argmax.
// ---------------------------------------------------------------------------
__global__ __launch_bounds__(64) void fps_kernel(
    const float* __restrict__ xyz,
    float* __restrict__ o_nx,     // new_xyz output region
    float* __restrict__ o_inds)   // inds output region (as float)
{
  __shared__ float sx[NPTS], sy[NPTS], sz[NPTS];
  __shared__ int   sInd[NPROP];

  const int b = blockIdx.x;
  const int t = threadIdx.x;              // 0..63
  const float* xb = xyz + b * NPTS * 3;
  for (int k = t; k < NPTS; k += 64) {
    sx[k] = xb[k*3+0];
    sy[k] = xb[k*3+1];
    sz[k] = xb[k*3+2];
  }
  __syncthreads();

  float px[16], py[16], pz[16], dd[16];
#pragma unroll
  for (int j = 0; j < 16; ++j) {
    int k = t + 64*j;
    px[j] = sx[k]; py[j] = sy[k]; pz[j] = sz[k];
    dd[j] = 1e10f;
  }

  int last = 0;
  for (int it = 1; it < NPROP; ++it) {
    float lx = sx[last], ly = sy[last], lz = sz[last];   // broadcast read
    float bv = -1.0f; int bi = 0;
#pragma unroll
    for (int j = 0; j < 16; ++j) {
      // IEEE, no FMA contraction: must match numpy sub/square/sum exactly
      float dx = __fsub_rn(px[j], lx);
      float dy = __fsub_rn(py[j], ly);
      float dz = __fsub_rn(pz[j], lz);
      float d  = __fadd_rn(__fadd_rn(__fmul_rn(dx,dx), __fmul_rn(dy,dy)), __fmul_rn(dz,dz));
      d = fminf(dd[j], d);
      dd[j] = d;
      if (d > bv) { bv = d; bi = t + 64*j; }   // ascending idx: strict > keeps lowest
    }
    // 64-lane butterfly argmax, tie -> lowest index (matches jnp.argmax)
#pragma unroll
    for (int m = 32; m >= 1; m >>= 1) {
      float v2 = __shfl_xor(bv, m);
      int   i2 = __shfl_xor(bi, m);
      if (v2 > bv || (v2 == bv && i2 < bi)) { bv = v2; bi = i2; }
    }
    last = bi;                 // all lanes agree
    if (t == 0) sInd[it] = bi;
  }
  if (t == 0) sInd[0] = 0;
  __syncthreads();

  for (int s = t; s < NPROP; s += 64) {
    int ind = sInd[s];
    o_inds[b*NPROP + s] = (float)ind;
    float* nx = o_nx + (b*NPROP + s)*3;
    nx[0] = sx[ind]; nx[1] = sy[ind]; nx[2] = sz[ind];
  }
}

// ---------------------------------------------------------------------------
// Kernel 1b: ball query — one wave per proposal, 16 contiguous pts per lane.
// Bitmask of hits + wave prefix-sum -> first 16 hits in ascending-k order.
// ---------------------------------------------------------------------------
__global__ __launch_bounds__(256) void bq_kernel(
    const float* __restrict__ xyz,
    const float* __restrict__ o_nx,
    int* __restrict__ ws_idx)
{
  const int lane = threadIdx.x & 63;
  const int wid  = threadIdx.x >> 6;      // 0..3
  const int bp   = blockIdx.x * 4 + wid;  // proposal id
  const int b    = bp >> 8;
  const float* xb = xyz + b * NPTS * 3;

  const float qx = o_nx[bp*3+0];
  const float qy = o_nx[bp*3+1];
  const float qz = o_nx[bp*3+2];

  const int k0 = lane * 16;
  unsigned mask = 0u;
#pragma unroll
  for (int j = 0; j < 16; ++j) {
    int k = k0 + j;
    float dx = __fsub_rn(qx, xb[k*3+0]);
    float dy = __fsub_rn(qy, xb[k*3+1]);
    float dz = __fsub_rn(qz, xb[k*3+2]);
    float d2 = __fadd_rn(__fadd_rn(__fmul_rn(dx,dx), __fmul_rn(dy,dy)), __fmul_rn(dz,dz));
    if (d2 < 0.09f) mask |= (1u << j);
  }
  int cnt  = __popc(mask);
  int incl = cnt;
#pragma unroll
  for (int ofs = 1; ofs < 64; ofs <<= 1) {
    int v = __shfl_up(incl, ofs);
    if (lane >= ofs) incl += v;
  }
  int start = incl - cnt;
  int total = __shfl(incl, 63);

  // first hit index (for padding); NPTS-1 if no hits at all
  int fc = mask ? (k0 + __ffs(mask) - 1) : 0x7fffffff;
#pragma unroll
  for (int m = 32; m >= 1; m >>= 1) fc = min(fc, __shfl_xor(fc, m));
  int first = (total > 0) ? fc : (NPTS - 1);

  const int base = bp * NSAMP;
  int pos = start;
  unsigned mm = mask;
  while (mm && pos < NSAMP) {
    int j = __ffs(mm) - 1; mm &= mm - 1;
    ws_idx[base + pos] = k0 + j;
    ++pos;
  }
  if (lane >= total && lane < NSAMP) ws_idx[base + lane] = first;
}

// ---------------------------------------------------------------------------
// Kernel 2: grouped MLP (259->128->128->128) + maxpool + FC head, one block/(b,p)
// ---------------------------------------------------------------------------
#define FMA16(xv, wv0, wv1, wv2, wv3, a) do { \
  a[0] = fmaf(xv.x, wv0.x, a[0]); a[1] = fmaf(xv.x, wv0.y, a[1]); \
  a[2] = fmaf(xv.x, wv0.z, a[2]); a[3] = fmaf(xv.x, wv0.w, a[3]); \
  a[0] = fmaf(xv.y, wv1.x, a[0]); a[1] = fmaf(xv.y, wv1.y, a[1]); \
  a[2] = fmaf(xv.y, wv1.z, a[2]); a[3] = fmaf(xv.y, wv1.w, a[3]); \
  a[0] = fmaf(xv.z, wv2.x, a[0]); a[1] = fmaf(xv.z, wv2.y, a[1]); \
  a[2] = fmaf(xv.z, wv2.z, a[2]); a[3] = fmaf(xv.z, wv2.w, a[3]); \
  a[0] = fmaf(xv.w, wv3.x, a[0]); a[1] = fmaf(xv.w, wv3.y, a[1]); \
  a[2] = fmaf(xv.w, wv3.z, a[2]); a[3] = fmaf(xv.w, wv3.w, a[3]); \
} while (0)

__device__ __forceinline__ void gemm_tile_128(
    const float* __restrict__ w, const float* src, int chg, float acc[4][4])
{
  const float4* wv4 = (const float4*)w;
  for (int c4 = 0; c4 < 32; ++c4) {
    float4 wv0 = wv4[(c4*4+0)*32 + chg];
    float4 wv1 = wv4[(c4*4+1)*32 + chg];
    float4 wv2 = wv4[(c4*4+2)*32 + chg];
    float4 wv3 = wv4[(c4*4+3)*32 + chg];
#pragma unroll
    for (int si = 0; si < 4; ++si) {
      float4 xv = *(const float4*)(src + si*YST + c4*4);
      FMA16(xv, wv0, wv1, wv2, wv3, acc[si]);
    }
  }
}

__global__ __launch_bounds__(128) void mlp_head_kernel(
    const float* __restrict__ xyz,  const float* __restrict__ feats,
    const float* __restrict__ msize,
    const float* __restrict__ w0,  const float* __restrict__ b0,
    const float* __restrict__ g0,  const float* __restrict__ be0,
    const float* __restrict__ w1,  const float* __restrict__ b1,
    const float* __restrict__ g1,  const float* __restrict__ be1,
    const float* __restrict__ w2,  const float* __restrict__ b2,
    const float* __restrict__ g2,  const float* __restrict__ be2,
    const float* __restrict__ wf1, const float* __restrict__ bf1,
    const float* __restrict__ gf1, const float* __restrict__ bef1,
    const float* __restrict__ wf2, const float* __restrict__ bf2,
    const float* __restrict__ gf2, const float* __restrict__ bef2,
    const float* __restrict__ w3,  const float* __restrict__ b3,
    const int* __restrict__ ws_idx,
    float* __restrict__ out)
{
  __shared__ float xb[16*XST];   // input tile; later reused as layer-1 output (zb)
  __shared__ float yb[16*YST];   // layer-0 output; later part/sfeat/sn1/sn2
  __shared__ int   sIdx[16];
  __shared__ float sq[3];

  const int t  = threadIdx.x;
  const int bp = blockIdx.x;
  const int b  = bp >> 8;

  if (t < 16) sIdx[t] = ws_idx[bp*16 + t];
  if (t >= 16 && t < 19) sq[t-16] = out[O_NX + bp*3 + (t-16)];
  __syncthreads();

  // stage gathered features: xb[s][0..255]
  {
    const int half = t >> 6;
    const int lane = t & 63;
#pragma unroll
    for (int s2 = 0; s2 < 8; ++s2) {
      int s = s2*2 + half;
      const float4* src = (const float4*)(feats + (size_t)(b*NPTS + sIdx[s]) * NFEAT);
      *((float4*)(xb + s*XST) + lane) = src[lane];
    }
  }
  // gxyz at xb[s][256..258]  (w rows 0..2)
  if (t < 48) {
    int s = t / 3, j = t - s*3;
    float v = xyz[(b*NPTS + sIdx[s])*3 + j];
    xb[s*XST + 256 + j] = (v - sq[j]) / 0.3f;
  }
  __syncthreads();

  const int sgrp = t >> 5;      // 0..3 : owns s rows sgrp*4..+3
  const int chg  = t & 31;      // 0..31: owns channels chg*4..+3
  const int ch0  = chg * 4;

  float acc[4][4];
#pragma unroll
  for (int i = 0; i < 4; ++i)
#pragma unroll
    for (int j = 0; j < 4; ++j) acc[i][j] = 0.0f;

  // ---- layer 0: 259 -> 128 (feat channels use w rows c+3; gxyz uses rows 0..2)
  {
    const float4* wv4 = (const float4*)w0;
    const float* xr = xb + sgrp*4*XST;
    for (int c4 = 0; c4 < 64; ++c4) {
      float4 wv0 = wv4[(c4*4+3)*32 + chg];
      float4 wv1 = wv4[(c4*4+4)*32 + chg];
      float4 wv2 = wv4[(c4*4+5)*32 + chg];
      float4 wv3 = wv4[(c4*4+6)*32 + chg];
#pragma unroll
      for (int si = 0; si < 4; ++si) {
        float4 xv = *(const float4*)(xr + si*XST + c4*4);
        FMA16(xv, wv0, wv1, wv2, wv3, acc[si]);
      }
    }
#pragma unroll
    for (int j = 0; j < 3; ++j) {
      float4 wv = wv4[j*32 + chg];
#pragma unroll
      for (int si = 0; si < 4; ++si) {
        float xv = xr[si*XST + 256 + j];
        acc[si][0] = fmaf(xv, wv.x, acc[si][0]);
        acc[si][1] = fmaf(xv, wv.y, acc[si][1]);
        acc[si][2] = fmaf(xv, wv.z, acc[si][2]);
        acc[si][3] = fmaf(xv, wv.w, acc[si][3]);
      }
    }
    float4 gg = *(const float4*)(g0 + ch0);
    float4 b4 = *(const float4*)(b0 + ch0);
    float4 e4 = *(const float4*)(be0 + ch0);
#pragma unroll
    for (int si = 0; si < 4; ++si) {
      float4 o;
      o.x = fmaxf(fmaf(gg.x, acc[si][0] + b4.x, e4.x), 0.0f);
      o.y = fmaxf(fmaf(gg.y, acc[si][1] + b4.y, e4.y), 0.0f);
      o.z = fmaxf(fmaf(gg.z, acc[si][2] + b4.z, e4.z), 0.0f);
      o.w = fmaxf(fmaf(gg.w, acc[si][3] + b4.w, e4.w), 0.0f);
      *(float4*)(yb + (sgrp*4+si)*YST + ch0) = o;
    }
  }
  __syncthreads();

  // ---- layer 1: 128 -> 128 (reads yb, writes zb = xb region)
  float* zb = xb;
  {
#pragma unroll
    for (int i = 0; i < 4; ++i)
#pragma unroll
      for (int j = 0; j < 4; ++j) acc[i][j] = 0.0f;
    gemm_tile_128(w1, yb + sgrp*4*YST, chg, acc);
    float4 gg = *(const float4*)(g1 + ch0);
    float4 b4 = *(const float4*)(b1 + ch0);
    float4 e4 = *(const float4*)(be1 + ch0);
#pragma unroll
    for (int si = 0; si < 4; ++si) {
      float4 o;
      o.x = fmaxf(fmaf(gg.x, acc[si][0] + b4.x, e4.x), 0.0f);
      o.y = fmaxf(fmaf(gg.y, acc[si][1] + b4.y, e4.y), 0.0f);
      o.z = fmaxf(fmaf(gg.z, acc[si][2] + b4.z, e4.z), 0.0f);
      o.w = fmaxf(fmaf(gg.w, acc[si][3] + b4.w, e4.w), 0.0f);
      *(float4*)(zb + (sgrp*4+si)*YST + ch0) = o;
    }
  }
  __syncthreads();

  // ---- layer 2: 128 -> 128, activation, per-thread max over its 4 s-rows
  {
#pragma unroll
    for (int i = 0; i < 4; ++i)
#pragma unroll
      for (int j = 0; j < 4; ++j) acc[i][j] = 0.0f;
    gemm_tile_128(w2, zb + sgrp*4*YST, chg, acc);
    float4 gg = *(const float4*)(g2 + ch0);
    float4 b4 = *(const float4*)(b2 + ch0);
    float4 e4 = *(const float4*)(be2 + ch0);
    float4 mx; mx.x = -1e30f; mx.y = -1e30f; mx.z = -1e30f; mx.w = -1e30f;
#pragma unroll
    for (int si = 0; si < 4; ++si) {
      mx.x = fmaxf(mx.x, fmaxf(fmaf(gg.x, acc[si][0] + b4.x, e4.x), 0.0f));
      mx.y = fmaxf(mx.y, fmaxf(fmaf(gg.y, acc[si][1] + b4.y, e4.y), 0.0f));
      mx.z = fmaxf(mx.z, fmaxf(fmaf(gg.z, acc[si][2] + b4.z, e4.z), 0.0f));
      mx.w = fmaxf(mx.w, fmaxf(fmaf(gg.w, acc[si][3] + b4.w, e4.w), 0.0f));
    }
    // part[sgrp][128] in yb[0..511]  (safe: all yb reads done before prior barrier)
    *(float4*)(yb + sgrp*128 + ch0) = mx;
  }
  __syncthreads();

  float* sfeat = yb + 512;
  {
    float f = yb[t];
    f = fmaxf(f, yb[128 + t]);
    f = fmaxf(f, yb[256 + t]);
    f = fmaxf(f, yb[384 + t]);
    sfeat[t] = f;
  }
  __syncthreads();

  // ---- FC1 (relu6)
  float* sn1 = yb + 640;
  {
    float a1 = 0.0f;
#pragma unroll
    for (int c4 = 0; c4 < 32; ++c4) {
      float4 fv = *(const float4*)(sfeat + c4*4);
      a1 = fmaf(fv.x, wf1[(c4*4+0)*128 + t], a1);
      a1 = fmaf(fv.y, wf1[(c4*4+1)*128 + t], a1);
      a1 = fmaf(fv.z, wf1[(c4*4+2)*128 + t], a1);
      a1 = fmaf(fv.w, wf1[(c4*4+3)*128 + t], a1);
    }
    float v = fminf(fmaxf(fmaf(gf1[t], a1 + bf1[t], bef1[t]), 0.0f), 6.0f);
    sn1[t] = v;
  }
  __syncthreads();

  // ---- FC2 (relu6)
  float* sn2 = yb + 768;
  {
    float a2 = 0.0f;
#pragma unroll
    for (int c4 = 0; c4 < 32; ++c4) {
      float4 fv = *(const float4*)(sn1 + c4*4);
      a2 = fmaf(fv.x, wf2[(c4*4+0)*128 + t], a2);
      a2 = fmaf(fv.y, wf2[(c4*4+1)*128 + t], a2);
      a2 = fmaf(fv.z, wf2[(c4*4+2)*128 + t], a2);
      a2 = fmaf(fv.w, wf2[(c4*4+3)*128 + t], a2);
    }
    float v = fminf(fmaxf(fmaf(gf2[t], a2 + bf2[t], bef2[t]), 0.0f), 6.0f);
    sn2[t] = v;
  }
  __syncthreads();

  // ---- FC3 (119 outputs) + scatter with per-head transforms
  if (t < 119) {
    float a3 = 0.0f;
#pragma unroll
    for (int c4 = 0; c4 < 32; ++c4) {
      float4 fv = *(const float4*)(sn2 + c4*4);
      a3 = fmaf(fv.x, w3[(c4*4+0)*119 + t], a3);
      a3 = fmaf(fv.y, w3[(c4*4+1)*119 + t], a3);
      a3 = fmaf(fv.z, w3[(c4*4+2)*119 + t], a3);
      a3 = fmaf(fv.w, w3[(c4*4+3)*119 + t], a3);
    }
    float v = a3 + b3[t];
    const float HRC = (float)(3.14159265359 / 12.0);
    if (t < 3) {
      out[O_CENTER + bp*3 + t] = sq[t] + v;
    } else if (t < 5) {
      out[O_OBJ + bp*2 + (t-3)] = v;
    } else if (t < 17) {
      out[O_HS + bp*12 + (t-5)] = v;
    } else if (t < 35) {
      out[O_SS + bp*18 + (t-17)] = v;
    } else if (t < 47) {
      int a = t - 35;
      out[O_HRN + bp*12 + a] = v;
      out[O_HR  + bp*12 + a] = v * HRC;
    } else if (t < 101) {
      int a = t - 47;
      out[O_SRN + bp*54 + a] = v;
      out[O_SR  + bp*54 + a] = v * msize[a];
    } else {
      int a = t - 101;
      out[O_SEM + bp*18 + a] = v;
    }
  }
}

// ---------------------------------------------------------------------------
extern "C" void kernel_launch(void* const* d_in, const int* in_sizes, int n_in,
                              void* d_out, int out_size, void* d_ws, size_t ws_size,
                              hipStream_t stream) {
  (void)in_sizes; (void)n_in; (void)out_size; (void)ws_size;
  const float* xyz   = (const float*)d_in[0];
  const float* feats = (const float*)d_in[1];
  const float* msize = (const float*)d_in[2];
  const float* w0  = (const float*)d_in[3];
  const float* b0  = (const float*)d_in[4];
  const float* g0  = (const float*)d_in[5];
  const float* be0 = (const float*)d_in[6];
  const float* w1  = (const float*)d_in[7];
  const float* b1  = (const float*)d_in[8];
  const float* g1  = (const float*)d_in[9];
  const float* be1 = (const float*)d_in[10];
  const float* w2  = (const float*)d_in[11];
  const float* b2  = (const float*)d_in[12];
  const float* g2  = (const float*)d_in[13];
  const float* be2 = (const float*)d_in[14];
  const float* wf1  = (const float*)d_in[15];
  const float* bf1  = (const float*)d_in[16];
  const float* gf1  = (const float*)d_in[17];
  const float* bef1 = (const float*)d_in[18];
  const float* wf2  = (const float*)d_in[19];
  const float* bf2  = (const float*)d_in[20];
  const float* gf2  = (const float*)d_in[21];
  const float* bef2 = (const float*)d_in[22];
  const float* w3 = (const float*)d_in[23];
  const float* b3 = (const float*)d_in[24];

  float* out = (float*)d_out;
  int* ws_idx = (int*)d_ws;   // B*P*NS ints = 512 KiB

  fps_kernel<<<BATCH, 64, 0, stream>>>(xyz, out + O_NX, out + O_INDS);
  bq_kernel<<<(BATCH*NPROP)/4, 256, 0, stream>>>(xyz, out + O_NX, ws_idx);
  mlp_head_kernel<<<BATCH*NPROP, 128, 0, stream>>>(
      xyz, feats, msize,
      w0, b0, g0, be0, w1, b1, g1, be1, w2, b2, g2, be2,
      wf1, bf1, gf1, bef1, wf2, bf2, gf2, bef2, w3, b3,
      ws_idx, out);
}

// Round 3
// 503.103 us; speedup vs baseline: 1.6807x; 1.3133x over previous
//
#include <hip/hip_runtime.h>

#define BATCH 32
#define NPTS  1024
#define NFEAT 256
#define NPROP 256
#define NSAMP 16

// flat output offsets (floats), in reference tuple order
#define O_OBJ    0
#define O_CENTER 16384
#define O_HS     40960
#define O_HRN    139264
#define O_HR     237568
#define O_SS     335872
#define O_SRN    483328
#define O_SR     925696
#define O_SEM    1368064
#define O_NX     1515520
#define O_INDS   1540096

typedef __attribute__((ext_vector_type(8))) short bf16x8;
typedef __attribute__((ext_vector_type(8))) unsigned short u16x8;
typedef __attribute__((ext_vector_type(4))) float f32x4;

__device__ __forceinline__ unsigned short f2bf(float f) {
  unsigned u = __builtin_bit_cast(unsigned, f);
  u += 0x7fffu + ((u >> 16) & 1u);   // RNE to bf16
  return (unsigned short)(u >> 16);
}

// ---------------------------------------------------------------------------
// Kernel 1: FPS — one wave per batch, 16 pts/lane in registers.
// Argmax reduction via DPP row_shr/row_bcast (VALU-only, no ds_bpermute chain).
// Bit-exact fp32 distances; first-max tie-break == jnp.argmax.
// ---------------------------------------------------------------------------
#define DPP_ARGMAX_STEP(CTRL) do {                                            \
  int _vv = __builtin_amdgcn_update_dpp(__builtin_bit_cast(int, bv),          \
            __builtin_bit_cast(int, bv), (CTRL), 0xf, 0xf, false);            \
  int _ii = __builtin_amdgcn_update_dpp(bi, bi, (CTRL), 0xf, 0xf, false);     \
  float _v2 = __builtin_bit_cast(float, _vv);                                 \
  if (_v2 > bv || (_v2 == bv && _ii < bi)) { bv = _v2; bi = _ii; }            \
} while (0)

__global__ __launch_bounds__(64) void fps_kernel(
    const float* __restrict__ xyz,
    float* __restrict__ o_nx,
    float* __restrict__ o_inds)
{
  __shared__ float sx[NPTS], sy[NPTS], sz[NPTS];
  __shared__ int   sInd[NPROP];

  const int b = blockIdx.x;
  const int t = threadIdx.x;              // 0..63
  const float* xb = xyz + b * NPTS * 3;
  for (int k = t; k < NPTS; k += 64) {
    sx[k] = xb[k*3+0];
    sy[k] = xb[k*3+1];
    sz[k] = xb[k*3+2];
  }
  __syncthreads();

  float px[16], py[16], pz[16], dd[16];
#pragma unroll
  for (int j = 0; j < 16; ++j) {
    int k = t + 64*j;
    px[j] = sx[k]; py[j] = sy[k]; pz[j] = sz[k];
    dd[j] = 1e10f;
  }

  int last = 0;
  for (int it = 1; it < NPROP; ++it) {
    float lx = sx[last], ly = sy[last], lz = sz[last];   // LDS broadcast
    float bv = -1.0f; int bi = 0;
#pragma unroll
    for (int j = 0; j < 16; ++j) {
      float dx = __fsub_rn(px[j], lx);
      float dy = __fsub_rn(py[j], ly);
      float dz = __fsub_rn(pz[j], lz);
      float d  = __fadd_rn(__fadd_rn(__fmul_rn(dx,dx), __fmul_rn(dy,dy)), __fmul_rn(dz,dz));
      d = fminf(dd[j], d);
      dd[j] = d;
      if (d > bv) { bv = d; bi = t + 64*j; }
    }
    // wave64 argmax to lane 63 via DPP (valid lanes combine; invalid keep old)
    DPP_ARGMAX_STEP(0x111);  // row_shr:1
    DPP_ARGMAX_STEP(0x112);  // row_shr:2
    DPP_ARGMAX_STEP(0x114);  // row_shr:4
    DPP_ARGMAX_STEP(0x118);  // row_shr:8
    DPP_ARGMAX_STEP(0x142);  // row_bcast:15
    DPP_ARGMAX_STEP(0x143);  // row_bcast:31
    last = __builtin_amdgcn_readlane(bi, 63);
    if (t == 0) sInd[it] = last;
  }
  if (t == 0) sInd[0] = 0;
  __syncthreads();

  for (int s = t; s < NPROP; s += 64) {
    int ind = sInd[s];
    o_inds[b*NPROP + s] = (float)ind;
    float* nx = o_nx + (b*NPROP + s)*3;
    nx[0] = sx[ind]; nx[1] = sy[ind]; nx[2] = sz[ind];
  }
}

// ---------------------------------------------------------------------------
// Kernel 1b: ball query — one wave per proposal (unchanged from R1).
// ---------------------------------------------------------------------------
__global__ __launch_bounds__(256) void bq_kernel(
    const float* __restrict__ xyz,
    const float* __restrict__ o_nx,
    int* __restrict__ ws_idx)
{
  const int lane = threadIdx.x & 63;
  const int wid  = threadIdx.x >> 6;
  const int bp   = blockIdx.x * 4 + wid;
  const int b    = bp >> 8;
  const float* xb = xyz + b * NPTS * 3;

  const float qx = o_nx[bp*3+0];
  const float qy = o_nx[bp*3+1];
  const float qz = o_nx[bp*3+2];

  const int k0 = lane * 16;
  unsigned mask = 0u;
#pragma unroll
  for (int j = 0; j < 16; ++j) {
    int k = k0 + j;
    float dx = __fsub_rn(qx, xb[k*3+0]);
    float dy = __fsub_rn(qy, xb[k*3+1]);
    float dz = __fsub_rn(qz, xb[k*3+2]);
    float d2 = __fadd_rn(__fadd_rn(__fmul_rn(dx,dx), __fmul_rn(dy,dy)), __fmul_rn(dz,dz));
    if (d2 < 0.09f) mask |= (1u << j);
  }
  int cnt  = __popc(mask);
  int incl = cnt;
#pragma unroll
  for (int ofs = 1; ofs < 64; ofs <<= 1) {
    int v = __shfl_up(incl, ofs);
    if (lane >= ofs) incl += v;
  }
  int start = incl - cnt;
  int total = __shfl(incl, 63);

  int fc = mask ? (k0 + __ffs(mask) - 1) : 0x7fffffff;
#pragma unroll
  for (int m = 32; m >= 1; m >>= 1) fc = min(fc, __shfl_xor(fc, m));
  int first = (total > 0) ? fc : (NPTS - 1);

  const int base = bp * NSAMP;
  int pos = start;
  unsigned mm = mask;
  while (mm && pos < NSAMP) {
    int j = __ffs(mm) - 1; mm &= mm - 1;
    ws_idx[base + pos] = k0 + j;
    ++pos;
  }
  if (lane >= total && lane < NSAMP) ws_idx[base + lane] = first;
}

// ---------------------------------------------------------------------------
// Prep kernels: feats -> bf16; mlp weights -> bf16 transposed B-layout [n][k]
// (w0 padded to K=288: k 0..255 = feat rows 3..258, k 256..258 = gxyz rows 0..2)
// w3 padded to [128][128] fp32.
// ---------------------------------------------------------------------------
__global__ __launch_bounds__(256) void prep_feats_kernel(
    const float* __restrict__ feats, unsigned short* __restrict__ fbf)
{
  size_t i = ((size_t)blockIdx.x * 256 + threadIdx.x) * 8;
  float4 f0 = *(const float4*)(feats + i);
  float4 f1 = *(const float4*)(feats + i + 4);
  u16x8 o;
  o[0]=f2bf(f0.x); o[1]=f2bf(f0.y); o[2]=f2bf(f0.z); o[3]=f2bf(f0.w);
  o[4]=f2bf(f1.x); o[5]=f2bf(f1.y); o[6]=f2bf(f1.z); o[7]=f2bf(f1.w);
  *(u16x8*)(fbf + i) = o;
}

__global__ __launch_bounds__(256) void prep_weights_kernel(
    const float* __restrict__ w0, const float* __restrict__ w1,
    const float* __restrict__ w2, const float* __restrict__ w3,
    unsigned short* __restrict__ w0bt, unsigned short* __restrict__ w1bt,
    unsigned short* __restrict__ w2bt, float* __restrict__ w3p)
{
  int id = blockIdx.x * 256 + threadIdx.x;
  if (id < 36864) {                       // w0bt [128][288]
    int n = id / 288, k = id - 288*n;
    float v = 0.f;
    if (k < 256) v = w0[(k+3)*128 + n];
    else if (k < 259) v = w0[(k-256)*128 + n];
    w0bt[id] = f2bf(v);
  } else if (id < 53248) {                // w1bt [128][128]
    int j = id - 36864; int n = j >> 7, k = j & 127;
    w1bt[j] = f2bf(w1[k*128 + n]);
  } else if (id < 69632) {                // w2bt [128][128]
    int j = id - 53248; int n = j >> 7, k = j & 127;
    w2bt[j] = f2bf(w2[k*128 + n]);
  } else if (id < 86016) {                // w3p [128][128] fp32, zero-padded
    int j = id - 69632; int k = j >> 7, c = j & 127;
    w3p[j] = (c < 119) ? w3[k*119 + c] : 0.f;
  }
}

// ---------------------------------------------------------------------------
// Kernel 2a: grouped MLP 259->128->128->128 + maxpool, bf16 MFMA, 1 wave/bp.
// A-frags loaded straight from global (lane's 8 bf16 contiguous in feat row).
// Inter-layer activations round-trip LDS in next-layer A-fragment order.
// ---------------------------------------------------------------------------
__global__ __launch_bounds__(64) void group_mlp_kernel(
    const float* __restrict__ xyz,
    const unsigned short* __restrict__ fbf,
    const unsigned short* __restrict__ w0bt,
    const unsigned short* __restrict__ w1bt,
    const unsigned short* __restrict__ w2bt,
    const float* __restrict__ b0, const float* __restrict__ g0, const float* __restrict__ be0,
    const float* __restrict__ b1, const float* __restrict__ g1, const float* __restrict__ be1,
    const float* __restrict__ b2, const float* __restrict__ g2, const float* __restrict__ be2,
    const int* __restrict__ ws_idx,
    const float* __restrict__ onx,
    float* __restrict__ featws)
{
  __shared__ __align__(16) unsigned short actA[2048];  // 4 KiB
  __shared__ __align__(16) unsigned short actB[2048];

  const int lane = threadIdx.x;
  const int m = lane & 15;         // A row (sample) / B col (channel) / D col
  const int q = lane >> 4;         // quad
  const int bp = blockIdx.x;
  const int b  = bp >> 8;

  const int idxm = ws_idx[bp*16 + m];
  const unsigned short* arow = fbf + ((size_t)(b*NPTS + idxm) << 8);

  f32x4 acc[8];
#pragma unroll
  for (int nt = 0; nt < 8; ++nt) acc[nt] = (f32x4){0.f,0.f,0.f,0.f};

  // ---- layer 0, K-blocks 0..7 (feature channels)
#pragma unroll
  for (int kb = 0; kb < 8; ++kb) {
    bf16x8 a = *(const bf16x8*)(arow + kb*32 + q*8);
    const unsigned short* wp = w0bt + m*288 + kb*32 + q*8;
#pragma unroll
    for (int nt = 0; nt < 8; ++nt) {
      bf16x8 bb = *(const bf16x8*)(wp + nt*16*288);
      acc[nt] = __builtin_amdgcn_mfma_f32_16x16x32_bf16(a, bb, acc[nt], 0, 0, 0);
    }
  }
  // ---- layer 0, K-block 8 (gxyz at k=256..258, rest zero)
  {
    bf16x8 a = (bf16x8){0,0,0,0,0,0,0,0};
    if (q == 0) {
      const float* p = xyz + (size_t)(b*NPTS + idxm)*3;
      float n0 = onx[bp*3+0], n1 = onx[bp*3+1], n2 = onx[bp*3+2];
      a[0] = (short)f2bf((p[0]-n0)*(1.0f/0.3f));
      a[1] = (short)f2bf((p[1]-n1)*(1.0f/0.3f));
      a[2] = (short)f2bf((p[2]-n2)*(1.0f/0.3f));
    }
    const unsigned short* wp = w0bt + m*288 + 256 + q*8;
#pragma unroll
    for (int nt = 0; nt < 8; ++nt) {
      bf16x8 bb = *(const bf16x8*)(wp + nt*16*288);
      acc[nt] = __builtin_amdgcn_mfma_f32_16x16x32_bf16(a, bb, acc[nt], 0, 0, 0);
    }
  }
  // ---- act0 -> actA (next-layer A-fragment order: slot = kb*64 + q'*16 + s)
#pragma unroll
  for (int nt = 0; nt < 8; ++nt) {
    int ch = nt*16 + m;
    float bb = b0[ch], gg = g0[ch], ee = be0[ch];
    int base = ((ch>>5)*64 + ((ch>>3)&3)*16)*8 + (ch&7);
#pragma unroll
    for (int r = 0; r < 4; ++r) {
      float v = fmaxf(fmaf(gg, acc[nt][r] + bb, ee), 0.f);
      actA[base + (q*4+r)*8] = f2bf(v);
    }
  }
  __syncthreads();

  // ---- layer 1
#pragma unroll
  for (int nt = 0; nt < 8; ++nt) acc[nt] = (f32x4){0.f,0.f,0.f,0.f};
#pragma unroll
  for (int kb = 0; kb < 4; ++kb) {
    bf16x8 a = *(const bf16x8*)(actA + (kb*64 + lane)*8);
    const unsigned short* wp = w1bt + m*128 + kb*32 + q*8;
#pragma unroll
    for (int nt = 0; nt < 8; ++nt) {
      bf16x8 bb = *(const bf16x8*)(wp + nt*2048);
      acc[nt] = __builtin_amdgcn_mfma_f32_16x16x32_bf16(a, bb, acc[nt], 0, 0, 0);
    }
  }
#pragma unroll
  for (int nt = 0; nt < 8; ++nt) {
    int ch = nt*16 + m;
    float bb = b1[ch], gg = g1[ch], ee = be1[ch];
    int base = ((ch>>5)*64 + ((ch>>3)&3)*16)*8 + (ch&7);
#pragma unroll
    for (int r = 0; r < 4; ++r) {
      float v = fmaxf(fmaf(gg, acc[nt][r] + bb, ee), 0.f);
      actB[base + (q*4+r)*8] = f2bf(v);
    }
  }
  __syncthreads();

  // ---- layer 2
#pragma unroll
  for (int nt = 0; nt < 8; ++nt) acc[nt] = (f32x4){0.f,0.f,0.f,0.f};
#pragma unroll
  for (int kb = 0; kb < 4; ++kb) {
    bf16x8 a = *(const bf16x8*)(actB + (kb*64 + lane)*8);
    const unsigned short* wp = w2bt + m*128 + kb*32 + q*8;
#pragma unroll
    for (int nt = 0; nt < 8; ++nt) {
      bf16x8 bb = *(const bf16x8*)(wp + nt*2048);
      acc[nt] = __builtin_amdgcn_mfma_f32_16x16x32_bf16(a, bb, acc[nt], 0, 0, 0);
    }
  }
  // ---- act2 + maxpool over 16 samples -> featws[bp][128]
  float mx[8];
#pragma unroll
  for (int nt = 0; nt < 8; ++nt) {
    int ch = nt*16 + m;
    float bb = b2[ch], gg = g2[ch], ee = be2[ch];
    float v0 = fmaxf(fmaf(gg, acc[nt][0] + bb, ee), 0.f);
    float v1 = fmaxf(fmaf(gg, acc[nt][1] + bb, ee), 0.f);
    float v2 = fmaxf(fmaf(gg, acc[nt][2] + bb, ee), 0.f);
    float v3 = fmaxf(fmaf(gg, acc[nt][3] + bb, ee), 0.f);
    float v = fmaxf(fmaxf(v0, v1), fmaxf(v2, v3));   // max over this quad's 4 rows
    v = fmaxf(v, __shfl_xor(v, 16));
    v = fmaxf(v, __shfl_xor(v, 32));
    mx[nt] = v;
  }
#pragma unroll
  for (int i = 0; i < 2; ++i) {
    int nt = q*2 + i;
    featws[(size_t)bp*128 + nt*16 + m] = mx[nt];
  }
}

// ---------------------------------------------------------------------------
// Kernel 2b: FC head batched over proposals — fp32, 32 rows/block, 256 thr.
// Thread (r,g): row r, output cols g*16..g*16+15.
// ---------------------------------------------------------------------------
#define FCS 132
__global__ __launch_bounds__(256) void fc_head_kernel(
    const float* __restrict__ featws,
    const float* __restrict__ onx,
    const float* __restrict__ msize,
    const float* __restrict__ wf1, const float* __restrict__ bf1,
    const float* __restrict__ gf1, const float* __restrict__ bef1,
    const float* __restrict__ wf2, const float* __restrict__ bf2,
    const float* __restrict__ gf2, const float* __restrict__ bef2,
    const float* __restrict__ w3p, const float* __restrict__ b3,
    float* __restrict__ out)
{
  __shared__ float A[32*FCS];
  __shared__ float Bb[32*FCS];
  const int t = threadIdx.x;
  const int r = t >> 3;
  const int g = t & 7;
  const int row0 = blockIdx.x * 32;

#pragma unroll
  for (int i = 0; i < 16; ++i) {
    int id = t + 256*i;
    int rr = id >> 7, cc = id & 127;
    A[rr*FCS + cc] = featws[(size_t)(row0+rr)*128 + cc];
  }
  __syncthreads();

  float acc[16];
  // ---- FC1 (relu6): A -> Bb
#pragma unroll
  for (int i = 0; i < 16; ++i) acc[i] = 0.f;
#pragma unroll 4
  for (int k = 0; k < 128; ++k) {
    float a = A[r*FCS + k];
    const float4* wv = (const float4*)(wf1 + k*128 + g*16);
    float4 v0 = wv[0], v1 = wv[1], v2 = wv[2], v3 = wv[3];
    acc[0]  = fmaf(a, v0.x, acc[0]);  acc[1]  = fmaf(a, v0.y, acc[1]);
    acc[2]  = fmaf(a, v0.z, acc[2]);  acc[3]  = fmaf(a, v0.w, acc[3]);
    acc[4]  = fmaf(a, v1.x, acc[4]);  acc[5]  = fmaf(a, v1.y, acc[5]);
    acc[6]  = fmaf(a, v1.z, acc[6]);  acc[7]  = fmaf(a, v1.w, acc[7]);
    acc[8]  = fmaf(a, v2.x, acc[8]);  acc[9]  = fmaf(a, v2.y, acc[9]);
    acc[10] = fmaf(a, v2.z, acc[10]); acc[11] = fmaf(a, v2.w, acc[11]);
    acc[12] = fmaf(a, v3.x, acc[12]); acc[13] = fmaf(a, v3.y, acc[13]);
    acc[14] = fmaf(a, v3.z, acc[14]); acc[15] = fmaf(a, v3.w, acc[15]);
  }
#pragma unroll
  for (int i = 0; i < 16; ++i) {
    int c = g*16 + i;
    Bb[r*FCS + c] = fminf(fmaxf(fmaf(gf1[c], acc[i] + bf1[c], bef1[c]), 0.f), 6.f);
  }
  __syncthreads();

  // ---- FC2 (relu6): Bb -> A
#pragma unroll
  for (int i = 0; i < 16; ++i) acc[i] = 0.f;
#pragma unroll 4
  for (int k = 0; k < 128; ++k) {
    float a = Bb[r*FCS + k];
    const float4* wv = (const float4*)(wf2 + k*128 + g*16);
    float4 v0 = wv[0], v1 = wv[1], v2 = wv[2], v3 = wv[3];
    acc[0]  = fmaf(a, v0.x, acc[0]);  acc[1]  = fmaf(a, v0.y, acc[1]);
    acc[2]  = fmaf(a, v0.z, acc[2]);  acc[3]  = fmaf(a, v0.w, acc[3]);
    acc[4]  = fmaf(a, v1.x, acc[4]);  acc[5]  = fmaf(a, v1.y, acc[5]);
    acc[6]  = fmaf(a, v1.z, acc[6]);  acc[7]  = fmaf(a, v1.w, acc[7]);
    acc[8]  = fmaf(a, v2.x, acc[8]);  acc[9]  = fmaf(a, v2.y, acc[9]);
    acc[10] = fmaf(a, v2.z, acc[10]); acc[11] = fmaf(a, v2.w, acc[11]);
    acc[12] = fmaf(a, v3.x, acc[12]); acc[13] = fmaf(a, v3.y, acc[13]);
    acc[14] = fmaf(a, v3.z, acc[14]); acc[15] = fmaf(a, v3.w, acc[15]);
  }
#pragma unroll
  for (int i = 0; i < 16; ++i) {
    int c = g*16 + i;
    A[r*FCS + c] = fminf(fmaxf(fmaf(gf2[c], acc[i] + bf2[c], bef2[c]), 0.f), 6.f);
  }
  __syncthreads();

  // ---- FC3: A -> 119 outs, scatter with transforms
#pragma unroll
  for (int i = 0; i < 16; ++i) acc[i] = 0.f;
#pragma unroll 4
  for (int k = 0; k < 128; ++k) {
    float a = A[r*FCS + k];
    const float4* wv = (const float4*)(w3p + k*128 + g*16);
    float4 v0 = wv[0], v1 = wv[1], v2 = wv[2], v3 = wv[3];
    acc[0]  = fmaf(a, v0.x, acc[0]);  acc[1]  = fmaf(a, v0.y, acc[1]);
    acc[2]  = fmaf(a, v0.z, acc[2]);  acc[3]  = fmaf(a, v0.w, acc[3]);
    acc[4]  = fmaf(a, v1.x, acc[4]);  acc[5]  = fmaf(a, v1.y, acc[5]);
    acc[6]  = fmaf(a, v1.z, acc[6]);  acc[7]  = fmaf(a, v1.w, acc[7]);
    acc[8]  = fmaf(a, v2.x, acc[8]);  acc[9]  = fmaf(a, v2.y, acc[9]);
    acc[10] = fmaf(a, v2.z, acc[10]); acc[11] = fmaf(a, v2.w, acc[11]);
    acc[12] = fmaf(a, v3.x, acc[12]); acc[13] = fmaf(a, v3.y, acc[13]);
    acc[14] = fmaf(a, v3.z, acc[14]); acc[15] = fmaf(a, v3.w, acc[15]);
  }
  const int bp = row0 + r;
  const float HRC = (float)(3.14159265359 / 12.0);
#pragma unroll
  for (int i = 0; i < 16; ++i) {
    int c = g*16 + i;
    if (c >= 119) continue;
    float v = acc[i] + b3[c];
    if (c < 3) {
      out[O_CENTER + bp*3 + c] = onx[bp*3 + c] + v;
    } else if (c < 5) {
      out[O_OBJ + bp*2 + (c-3)] = v;
    } else if (c < 17) {
      out[O_HS + bp*12 + (c-5)] = v;
    } else if (c < 35) {
      out[O_SS + bp*18 + (c-17)] = v;
    } else if (c < 47) {
      int a2 = c - 35;
      out[O_HRN + bp*12 + a2] = v;
      out[O_HR  + bp*12 + a2] = v * HRC;
    } else if (c < 101) {
      int a2 = c - 47;
      out[O_SRN + bp*54 + a2] = v;
      out[O_SR  + bp*54 + a2] = v * msize[a2];
    } else {
      int a2 = c - 101;
      out[O_SEM + bp*18 + a2] = v;
    }
  }
}

// ---------------------------------------------------------------------------
extern "C" void kernel_launch(void* const* d_in, const int* in_sizes, int n_in,
                              void* d_out, int out_size, void* d_ws, size_t ws_size,
                              hipStream_t stream) {
  (void)in_sizes; (void)n_in; (void)out_size; (void)ws_size;
  const float* xyz   = (const float*)d_in[0];
  const float* feats = (const float*)d_in[1];
  const float* msize = (const float*)d_in[2];
  const float* w0  = (const float*)d_in[3];
  const float* b0  = (const float*)d_in[4];
  const float* g0  = (const float*)d_in[5];
  const float* be0 = (const float*)d_in[6];
  const float* w1  = (const float*)d_in[7];
  const float* b1  = (const float*)d_in[8];
  const float* g1  = (const float*)d_in[9];
  const float* be1 = (const float*)d_in[10];
  const float* w2  = (const float*)d_in[11];
  const float* b2  = (const float*)d_in[12];
  const float* g2  = (const float*)d_in[13];
  const float* be2 = (const float*)d_in[14];
  const float* wf1  = (const float*)d_in[15];
  const float* bf1  = (const float*)d_in[16];
  const float* gf1  = (const float*)d_in[17];
  const float* bef1 = (const float*)d_in[18];
  const float* wf2  = (const float*)d_in[19];
  const float* bf2  = (const float*)d_in[20];
  const float* gf2  = (const float*)d_in[21];
  const float* bef2 = (const float*)d_in[22];
  const float* w3 = (const float*)d_in[23];
  const float* b3 = (const float*)d_in[24];

  float* out = (float*)d_out;

  // workspace layout (bytes)
  char* wsb = (char*)d_ws;
  int*            ws_idx = (int*)           (wsb + 0);          //  512 KiB
  unsigned short* fbf    = (unsigned short*)(wsb + 524288);     // 16 MiB
  float*          featws = (float*)         (wsb + 17301504);   //  4 MiB
  unsigned short* w0bt   = (unsigned short*)(wsb + 21495808);   //  72 KiB
  unsigned short* w1bt   = (unsigned short*)(wsb + 21569536);   //  32 KiB
  unsigned short* w2bt   = (unsigned short*)(wsb + 21602304);   //  32 KiB
  float*          w3p    = (float*)         (wsb + 21635072);   //  64 KiB

  fps_kernel<<<BATCH, 64, 0, stream>>>(xyz, out + O_NX, out + O_INDS);
  bq_kernel<<<(BATCH*NPROP)/4, 256, 0, stream>>>(xyz, out + O_NX, ws_idx);
  prep_feats_kernel<<<(BATCH*NPTS*NFEAT)/(8*256), 256, 0, stream>>>(feats, fbf);
  prep_weights_kernel<<<336, 256, 0, stream>>>(w0, w1, w2, w3, w0bt, w1bt, w2bt, w3p);
  group_mlp_kernel<<<BATCH*NPROP, 64, 0, stream>>>(
      xyz, fbf, w0bt, w1bt, w2bt,
      b0, g0, be0, b1, g1, be1, b2, g2, be2,
      ws_idx, out + O_NX, featws);
  fc_head_kernel<<<(BATCH*NPROP)/32, 256, 0, stream>>>(
      featws, out + O_NX, msize,
      wf1, bf1, gf1, bef1, wf2, bf2, gf2, bef2, w3p, b3, out);
}

// Round 4
// 474.140 us; speedup vs baseline: 1.7834x; 1.0611x over previous
//
#include <hip/hip_runtime.h>

#define BATCH 32
#define NPTS  1024
#define NFEAT 256
#define NPROP 256
#define NSAMP 16

// flat output offsets (floats), in reference tuple order
#define O_OBJ    0
#define O_CENTER 16384
#define O_HS     40960
#define O_HRN    139264
#define O_HR     237568
#define O_SS     335872
#define O_SRN    483328
#define O_SR     925696
#define O_SEM    1368064
#define O_NX     1515520
#define O_INDS   1540096

typedef __attribute__((ext_vector_type(8))) short bf16x8;
typedef __attribute__((ext_vector_type(8))) unsigned short u16x8;
typedef __attribute__((ext_vector_type(2))) float f32x2;
typedef __attribute__((ext_vector_type(4))) float f32x4;
typedef __attribute__((ext_vector_type(16))) float f32x16;

__device__ __forceinline__ unsigned short f2bf(float f) {
  unsigned u = __builtin_bit_cast(unsigned, f);
  u += 0x7fffu + ((u >> 16) & 1u);   // RNE to bf16
  return (unsigned short)(u >> 16);
}

// ---------------------------------------------------------------------------
// Kernel 1: FPS — one wave per batch, 16 pts/lane in registers.
// Distances computed as packed float2 pairs (v_pk_*_f32, still exact IEEE RNE
// per half, contraction off) to cut serial-path instruction count.
// Argmax via DPP row_shr/row_bcast; first-max tie-break == jnp.argmax.
// ---------------------------------------------------------------------------
#define DPP_ARGMAX_STEP(CTRL) do {                                            \
  int _vv = __builtin_amdgcn_update_dpp(__builtin_bit_cast(int, bv),          \
            __builtin_bit_cast(int, bv), (CTRL), 0xf, 0xf, false);            \
  int _ii = __builtin_amdgcn_update_dpp(bi, bi, (CTRL), 0xf, 0xf, false);     \
  float _v2 = __builtin_bit_cast(float, _vv);                                 \
  if (_v2 > bv || (_v2 == bv && _ii < bi)) { bv = _v2; bi = _ii; }            \
} while (0)

__global__ __launch_bounds__(64) void fps_kernel(
    const float* __restrict__ xyz,
    float* __restrict__ o_nx,
    float* __restrict__ o_inds)
{
#pragma clang fp contract(off)
  __shared__ float sxyz[NPTS*3];
  __shared__ int   sInd[NPROP];

  const int b = blockIdx.x;
  const int t = threadIdx.x;              // 0..63
  const float* xb = xyz + b * NPTS * 3;
  for (int i = t; i < NPTS*3; i += 64) sxyz[i] = xb[i];
  __syncthreads();

  // pair a holds points k0 = t+128a (lo) and k1 = k0+64 (hi)
  f32x2 px[8], py[8], pz[8], dd[8];
#pragma unroll
  for (int a = 0; a < 8; ++a) {
    int k0 = t + 128*a, k1 = k0 + 64;
    px[a] = (f32x2){sxyz[k0*3+0], sxyz[k1*3+0]};
    py[a] = (f32x2){sxyz[k0*3+1], sxyz[k1*3+1]};
    pz[a] = (f32x2){sxyz[k0*3+2], sxyz[k1*3+2]};
    dd[a] = (f32x2){1e10f, 1e10f};
  }

  int last = 0;
  for (int it = 1; it < NPROP; ++it) {
    float lx = sxyz[last*3+0], ly = sxyz[last*3+1], lz = sxyz[last*3+2];
    f32x2 vlx = (f32x2){lx, lx}, vly = (f32x2){ly, ly}, vlz = (f32x2){lz, lz};
    float bv = -1.0f; int bi = 0;
#pragma unroll
    for (int a = 0; a < 8; ++a) {
      f32x2 dx = px[a] - vlx;
      f32x2 dy = py[a] - vly;
      f32x2 dz = pz[a] - vlz;
      f32x2 d  = dx*dx + dy*dy + dz*dz;     // contract off: mul,mul,mul,add,add
      d = __builtin_elementwise_min(dd[a], d);
      dd[a] = d;
      if (d[0] > bv) { bv = d[0]; bi = t + 128*a; }        // lo index first
      if (d[1] > bv) { bv = d[1]; bi = t + 128*a + 64; }   // strict >: first-max
    }
    DPP_ARGMAX_STEP(0x111);  // row_shr:1
    DPP_ARGMAX_STEP(0x112);  // row_shr:2
    DPP_ARGMAX_STEP(0x114);  // row_shr:4
    DPP_ARGMAX_STEP(0x118);  // row_shr:8
    DPP_ARGMAX_STEP(0x142);  // row_bcast:15
    DPP_ARGMAX_STEP(0x143);  // row_bcast:31
    last = __builtin_amdgcn_readlane(bi, 63);
    if (t == 0) sInd[it] = last;
  }
  if (t == 0) sInd[0] = 0;
  __syncthreads();

  for (int s = t; s < NPROP; s += 64) {
    int ind = sInd[s];
    o_inds[b*NPROP + s] = (float)ind;
    float* nx = o_nx + (b*NPROP + s)*3;
    nx[0] = sxyz[ind*3+0]; nx[1] = sxyz[ind*3+1]; nx[2] = sxyz[ind*3+2];
  }
}

// ---------------------------------------------------------------------------
// Kernel 1b: ball query — one wave per proposal (unchanged; passed exact).
// ---------------------------------------------------------------------------
__global__ __launch_bounds__(256) void bq_kernel(
    const float* __restrict__ xyz,
    const float* __restrict__ o_nx,
    int* __restrict__ ws_idx)
{
  const int lane = threadIdx.x & 63;
  const int wid  = threadIdx.x >> 6;
  const int bp   = blockIdx.x * 4 + wid;
  const int b    = bp >> 8;
  const float* xb = xyz + b * NPTS * 3;

  const float qx = o_nx[bp*3+0];
  const float qy = o_nx[bp*3+1];
  const float qz = o_nx[bp*3+2];

  const int k0 = lane * 16;
  unsigned mask = 0u;
#pragma unroll
  for (int j = 0; j < 16; ++j) {
    int k = k0 + j;
    float dx = __fsub_rn(qx, xb[k*3+0]);
    float dy = __fsub_rn(qy, xb[k*3+1]);
    float dz = __fsub_rn(qz, xb[k*3+2]);
    float d2 = __fadd_rn(__fadd_rn(__fmul_rn(dx,dx), __fmul_rn(dy,dy)), __fmul_rn(dz,dz));
    if (d2 < 0.09f) mask |= (1u << j);
  }
  int cnt  = __popc(mask);
  int incl = cnt;
#pragma unroll
  for (int ofs = 1; ofs < 64; ofs <<= 1) {
    int v = __shfl_up(incl, ofs);
    if (lane >= ofs) incl += v;
  }
  int start = incl - cnt;
  int total = __shfl(incl, 63);

  int fc = mask ? (k0 + __ffs(mask) - 1) : 0x7fffffff;
#pragma unroll
  for (int m = 32; m >= 1; m >>= 1) fc = min(fc, __shfl_xor(fc, m));
  int first = (total > 0) ? fc : (NPTS - 1);

  const int base = bp * NSAMP;
  int pos = start;
  unsigned mm = mask;
  while (mm && pos < NSAMP) {
    int j = __ffs(mm) - 1; mm &= mm - 1;
    ws_idx[base + pos] = k0 + j;
    ++pos;
  }
  if (lane >= total && lane < NSAMP) ws_idx[base + lane] = first;
}

// ---------------------------------------------------------------------------
// Merged prep: feats->bf16; weights -> bf16 B-layout [n][k]; gb = g*b+be.
// w0bt [128][288]: k 0..255 = w0 rows 3..258 (feat), 256..258 = rows 0..2
// (gxyz), 259..287 = 0.  w3p [128][128] fp32 zero-padded.
// ---------------------------------------------------------------------------
__global__ __launch_bounds__(256) void prep_kernel(
    const float* __restrict__ feats, unsigned short* __restrict__ fbf,
    const float* __restrict__ w0, const float* __restrict__ w1,
    const float* __restrict__ w2, const float* __restrict__ w3,
    const float* __restrict__ b0, const float* __restrict__ g0, const float* __restrict__ be0,
    const float* __restrict__ b1, const float* __restrict__ g1, const float* __restrict__ be1,
    const float* __restrict__ b2, const float* __restrict__ g2, const float* __restrict__ be2,
    unsigned short* __restrict__ w0bt, unsigned short* __restrict__ w1bt,
    unsigned short* __restrict__ w2bt, float* __restrict__ w3p,
    float* __restrict__ gb0, float* __restrict__ gb1, float* __restrict__ gb2)
{
  if (blockIdx.x < 4096) {
    size_t i = ((size_t)blockIdx.x * 256 + threadIdx.x) * 8;
    float4 f0 = *(const float4*)(feats + i);
    float4 f1 = *(const float4*)(feats + i + 4);
    u16x8 o;
    o[0]=f2bf(f0.x); o[1]=f2bf(f0.y); o[2]=f2bf(f0.z); o[3]=f2bf(f0.w);
    o[4]=f2bf(f1.x); o[5]=f2bf(f1.y); o[6]=f2bf(f1.z); o[7]=f2bf(f1.w);
    *(u16x8*)(fbf + i) = o;
    return;
  }
  int id = (blockIdx.x - 4096) * 256 + threadIdx.x;
  if (id < 36864) {                       // w0bt [128][288]
    int n = id / 288, k = id - 288*n;
    float v = 0.f;
    if (k < 256) v = w0[(k+3)*128 + n];
    else if (k < 259) v = w0[(k-256)*128 + n];
    w0bt[id] = f2bf(v);
  } else if (id < 53248) {                // w1bt [128][128]
    int j = id - 36864; int n = j >> 7, k = j & 127;
    w1bt[j] = f2bf(w1[k*128 + n]);
  } else if (id < 69632) {                // w2bt [128][128]
    int j = id - 53248; int n = j >> 7, k = j & 127;
    w2bt[j] = f2bf(w2[k*128 + n]);
  } else if (id < 86016) {                // w3p [128][128] fp32, zero-padded
    int j = id - 69632; int k = j >> 7, c = j & 127;
    w3p[j] = (c < 119) ? w3[k*119 + c] : 0.f;
  } else if (id < 86144) {
    int c = id - 86016; gb0[c] = fmaf(g0[c], b0[c], be0[c]);
  } else if (id < 86272) {
    int c = id - 86144; gb1[c] = fmaf(g1[c], b1[c], be1[c]);
  } else if (id < 86400) {
    int c = id - 86272; gb2[c] = fmaf(g2[c], b2[c], be2[c]);
  }
}

// ---------------------------------------------------------------------------
// Kernel 2a: grouped MLP via 32x32x16 bf16 MFMA — 1 wave per 2 proposals.
// A rows = 32 samples (2 proposals x 16), N-tiles = 4 (128 ch).
// Layer interface: bank-swizzled LDS act buffer, element (s,c) at
//   E(s,c) = (c>>3)*256 + ((s + 2*(c>>3)) & 31)*8 + (c&7)
// so next-layer A-frag (lane s, half h, kstep) is one contiguous 16B read.
// ---------------------------------------------------------------------------
__global__ __launch_bounds__(64, 3) void group_mlp_kernel(
    const float* __restrict__ xyz,
    const unsigned short* __restrict__ fbf,
    const unsigned short* __restrict__ w0bt,
    const unsigned short* __restrict__ w1bt,
    const unsigned short* __restrict__ w2bt,
    const float* __restrict__ g0, const float* __restrict__ gb0,
    const float* __restrict__ g1, const float* __restrict__ gb1,
    const float* __restrict__ g2, const float* __restrict__ gb2,
    const int* __restrict__ ws_idx,
    const float* __restrict__ onx,
    float* __restrict__ featws)
{
  __shared__ __align__(16) unsigned short act[4096];   // 8 KiB

  const int lane = threadIdx.x;
  const int s  = lane & 31;        // A row (sample) / B-D col bits (channel)
  const int h  = lane >> 5;        // K-half
  const int n0 = s;                // channel lane for B/D
  const int p  = blockIdx.x * 2 + (s >> 4);   // this lane's A-row proposal
  const int b  = blockIdx.x >> 7;             // batch
  const int samp = s & 15;

  const int idx = ws_idx[p*16 + samp];
  const unsigned short* arow = fbf + ((size_t)(b*NPTS + idx) << 8);

  // gxyz A-fragment for kstep 16 (k=256..258 live in h==0 lanes)
  bf16x8 agx = (bf16x8){0,0,0,0,0,0,0,0};
  if (h == 0) {
    const float* pp = xyz + (size_t)(b*NPTS + idx)*3;
    agx[0] = (short)f2bf((pp[0] - onx[p*3+0]) * (1.0f/0.3f));
    agx[1] = (short)f2bf((pp[1] - onx[p*3+1]) * (1.0f/0.3f));
    agx[2] = (short)f2bf((pp[2] - onx[p*3+2]) * (1.0f/0.3f));
  }

  f32x16 acc[4];
#pragma unroll
  for (int nt = 0; nt < 4; ++nt) acc[nt] = (f32x16)(0.f);

  // ---- layer 0: K = 259 (ksteps 0..15 feats, 16 = gxyz; kstep 17 all-zero skipped)
  for (int ks = 0; ks < 16; ++ks) {
    bf16x8 a = *(const bf16x8*)(arow + ks*16 + h*8);
    const unsigned short* wp = w0bt + (size_t)n0*288 + ks*16 + h*8;
#pragma unroll
    for (int nt = 0; nt < 4; ++nt) {
      bf16x8 bb = *(const bf16x8*)(wp + (size_t)nt*32*288);
      acc[nt] = __builtin_amdgcn_mfma_f32_32x32x16_bf16(a, bb, acc[nt], 0, 0, 0);
    }
  }
  {
    const unsigned short* wp = w0bt + (size_t)n0*288 + 256 + h*8;
#pragma unroll
    for (int nt = 0; nt < 4; ++nt) {
      bf16x8 bb = *(const bf16x8*)(wp + (size_t)nt*32*288);
      acc[nt] = __builtin_amdgcn_mfma_f32_32x32x16_bf16(agx, bb, acc[nt], 0, 0, 0);
    }
  }
  // act0 -> LDS (relu(g*x+gb)), swizzled layout
#pragma unroll
  for (int nt = 0; nt < 4; ++nt) {
    int c = nt*32 + n0;
    int gch = c >> 3;
    float gg = g0[c], gv = gb0[c];
    int base = gch*256 + (c & 7);
#pragma unroll
    for (int r = 0; r < 16; ++r) {
      int srow = (r & 3) + 8*(r >> 2) + 4*h;
      float v = fmaxf(fmaf(gg, acc[nt][r], gv), 0.f);
      act[base + ((srow + 2*gch) & 31)*8] = f2bf(v);
    }
  }
  __syncthreads();

  // ---- layer 1: K = 128
#pragma unroll
  for (int nt = 0; nt < 4; ++nt) acc[nt] = (f32x16)(0.f);
  for (int ks = 0; ks < 8; ++ks) {
    int g = ks*2 + h;
    bf16x8 a = *(const bf16x8*)(act + g*256 + ((s + 2*g) & 31)*8);
    const unsigned short* wp = w1bt + (size_t)n0*128 + ks*16 + h*8;
#pragma unroll
    for (int nt = 0; nt < 4; ++nt) {
      bf16x8 bb = *(const bf16x8*)(wp + (size_t)nt*32*128);
      acc[nt] = __builtin_amdgcn_mfma_f32_32x32x16_bf16(a, bb, acc[nt], 0, 0, 0);
    }
  }
  __syncthreads();
#pragma unroll
  for (int nt = 0; nt < 4; ++nt) {
    int c = nt*32 + n0;
    int gch = c >> 3;
    float gg = g1[c], gv = gb1[c];
    int base = gch*256 + (c & 7);
#pragma unroll
    for (int r = 0; r < 16; ++r) {
      int srow = (r & 3) + 8*(r >> 2) + 4*h;
      float v = fmaxf(fmaf(gg, acc[nt][r], gv), 0.f);
      act[base + ((srow + 2*gch) & 31)*8] = f2bf(v);
    }
  }
  __syncthreads();

  // ---- layer 2: K = 128, fused maxpool over each proposal's 16 samples
#pragma unroll
  for (int nt = 0; nt < 4; ++nt) acc[nt] = (f32x16)(0.f);
  for (int ks = 0; ks < 8; ++ks) {
    int g = ks*2 + h;
    bf16x8 a = *(const bf16x8*)(act + g*256 + ((s + 2*g) & 31)*8);
    const unsigned short* wp = w2bt + (size_t)n0*128 + ks*16 + h*8;
#pragma unroll
    for (int nt = 0; nt < 4; ++nt) {
      bf16x8 bb = *(const bf16x8*)(wp + (size_t)nt*32*128);
      acc[nt] = __builtin_amdgcn_mfma_f32_32x32x16_bf16(a, bb, acc[nt], 0, 0, 0);
    }
  }
#pragma unroll
  for (int nt = 0; nt < 4; ++nt) {
    int c = nt*32 + n0;
    float gg = g2[c], gv = gb2[c];
    float m0 = 0.f, m1 = 0.f;   // relu => max >= 0
#pragma unroll
    for (int r = 0; r < 8; ++r)
      m0 = fmaxf(m0, fmaxf(fmaf(gg, acc[nt][r], gv), 0.f));       // rows 0..15  (prop lo)
#pragma unroll
    for (int r = 8; r < 16; ++r)
      m1 = fmaxf(m1, fmaxf(fmaf(gg, acc[nt][r], gv), 0.f));       // rows 16..31 (prop hi)
    m0 = fmaxf(m0, __shfl_xor(m0, 32));
    m1 = fmaxf(m1, __shfl_xor(m1, 32));
    float vout = h ? m1 : m0;
    featws[(size_t)(blockIdx.x*2 + h)*128 + c] = vout;
  }
}

// ---------------------------------------------------------------------------
// Kernel 2b: FC head batched over proposals — fp32, 32 rows/block, 256 thr.
// ---------------------------------------------------------------------------
#define FCS 132
__global__ __launch_bounds__(256) void fc_head_kernel(
    const float* __restrict__ featws,
    const float* __restrict__ onx,
    const float* __restrict__ msize,
    const float* __restrict__ wf1, const float* __restrict__ bf1,
    const float* __restrict__ gf1, const float* __restrict__ bef1,
    const float* __restrict__ wf2, const float* __restrict__ bf2,
    const float* __restrict__ gf2, const float* __restrict__ bef2,
    const float* __restrict__ w3p, const float* __restrict__ b3,
    float* __restrict__ out)
{
  __shared__ float A[32*FCS];
  __shared__ float Bb[32*FCS];
  const int t = threadIdx.x;
  const int r = t >> 3;
  const int g = t & 7;
  const int row0 = blockIdx.x * 32;

#pragma unroll
  for (int i = 0; i < 16; ++i) {
    int id = t + 256*i;
    int rr = id >> 7, cc = id & 127;
    A[rr*FCS + cc] = featws[(size_t)(row0+rr)*128 + cc];
  }
  __syncthreads();

  float acc[16];
  // ---- FC1 (relu6): A -> Bb
#pragma unroll
  for (int i = 0; i < 16; ++i) acc[i] = 0.f;
#pragma unroll 4
  for (int k = 0; k < 128; ++k) {
    float a = A[r*FCS + k];
    const float4* wv = (const float4*)(wf1 + k*128 + g*16);
    float4 v0 = wv[0], v1 = wv[1], v2 = wv[2], v3 = wv[3];
    acc[0]  = fmaf(a, v0.x, acc[0]);  acc[1]  = fmaf(a, v0.y, acc[1]);
    acc[2]  = fmaf(a, v0.z, acc[2]);  acc[3]  = fmaf(a, v0.w, acc[3]);
    acc[4]  = fmaf(a, v1.x, acc[4]);  acc[5]  = fmaf(a, v1.y, acc[5]);
    acc[6]  = fmaf(a, v1.z, acc[6]);  acc[7]  = fmaf(a, v1.w, acc[7]);
    acc[8]  = fmaf(a, v2.x, acc[8]);  acc[9]  = fmaf(a, v2.y, acc[9]);
    acc[10] = fmaf(a, v2.z, acc[10]); acc[11] = fmaf(a, v2.w, acc[11]);
    acc[12] = fmaf(a, v3.x, acc[12]); acc[13] = fmaf(a, v3.y, acc[13]);
    acc[14] = fmaf(a, v3.z, acc[14]); acc[15] = fmaf(a, v3.w, acc[15]);
  }
#pragma unroll
  for (int i = 0; i < 16; ++i) {
    int c = g*16 + i;
    Bb[r*FCS + c] = fminf(fmaxf(fmaf(gf1[c], acc[i] + bf1[c], bef1[c]), 0.f), 6.f);
  }
  __syncthreads();

  // ---- FC2 (relu6): Bb -> A
#pragma unroll
  for (int i = 0; i < 16; ++i) acc[i] = 0.f;
#pragma unroll 4
  for (int k = 0; k < 128; ++k) {
    float a = Bb[r*FCS + k];
    const float4* wv = (const float4*)(wf2 + k*128 + g*16);
    float4 v0 = wv[0], v1 = wv[1], v2 = wv[2], v3 = wv[3];
    acc[0]  = fmaf(a, v0.x, acc[0]);  acc[1]  = fmaf(a, v0.y, acc[1]);
    acc[2]  = fmaf(a, v0.z, acc[2]);  acc[3]  = fmaf(a, v0.w, acc[3]);
    acc[4]  = fmaf(a, v1.x, acc[4]);  acc[5]  = fmaf(a, v1.y, acc[5]);
    acc[6]  = fmaf(a, v1.z, acc[6]);  acc[7]  = fmaf(a, v1.w, acc[7]);
    acc[8]  = fmaf(a, v2.x, acc[8]);  acc[9]  = fmaf(a, v2.y, acc[9]);
    acc[10] = fmaf(a, v2.z, acc[10]); acc[11] = fmaf(a, v2.w, acc[11]);
    acc[12] = fmaf(a, v3.x, acc[12]); acc[13] = fmaf(a, v3.y, acc[13]);
    acc[14] = fmaf(a, v3.z, acc[14]); acc[15] = fmaf(a, v3.w, acc[15]);
  }
#pragma unroll
  for (int i = 0; i < 16; ++i) {
    int c = g*16 + i;
    A[r*FCS + c] = fminf(fmaxf(fmaf(gf2[c], acc[i] + bf2[c], bef2[c]), 0.f), 6.f);
  }
  __syncthreads();

  // ---- FC3: A -> 119 outs, scatter with transforms
#pragma unroll
  for (int i = 0; i < 16; ++i) acc[i] = 0.f;
#pragma unroll 4
  for (int k = 0; k < 128; ++k) {
    float a = A[r*FCS + k];
    const float4* wv = (const float4*)(w3p + k*128 + g*16);
    float4 v0 = wv[0], v1 = wv[1], v2 = wv[2], v3 = wv[3];
    acc[0]  = fmaf(a, v0.x, acc[0]);  acc[1]  = fmaf(a, v0.y, acc[1]);
    acc[2]  = fmaf(a, v0.z, acc[2]);  acc[3]  = fmaf(a, v0.w, acc[3]);
    acc[4]  = fmaf(a, v1.x, acc[4]);  acc[5]  = fmaf(a, v1.y, acc[5]);
    acc[6]  = fmaf(a, v1.z, acc[6]);  acc[7]  = fmaf(a, v1.w, acc[7]);
    acc[8]  = fmaf(a, v2.x, acc[8]);  acc[9]  = fmaf(a, v2.y, acc[9]);
    acc[10] = fmaf(a, v2.z, acc[10]); acc[11] = fmaf(a, v2.w, acc[11]);
    acc[12] = fmaf(a, v3.x, acc[12]); acc[13] = fmaf(a, v3.y, acc[13]);
    acc[14] = fmaf(a, v3.z, acc[14]); acc[15] = fmaf(a, v3.w, acc[15]);
  }
  const int bp = row0 + r;
  const float HRC = (float)(3.14159265359 / 12.0);
#pragma unroll
  for (int i = 0; i < 16; ++i) {
    int c = g*16 + i;
    if (c >= 119) continue;
    float v = acc[i] + b3[c];
    if (c < 3) {
      out[O_CENTER + bp*3 + c] = onx[bp*3 + c] + v;
    } else if (c < 5) {
      out[O_OBJ + bp*2 + (c-3)] = v;
    } else if (c < 17) {
      out[O_HS + bp*12 + (c-5)] = v;
    } else if (c < 35) {
      out[O_SS + bp*18 + (c-17)] = v;
    } else if (c < 47) {
      int a2 = c - 35;
      out[O_HRN + bp*12 + a2] = v;
      out[O_HR  + bp*12 + a2] = v * HRC;
    } else if (c < 101) {
      int a2 = c - 47;
      out[O_SRN + bp*54 + a2] = v;
      out[O_SR  + bp*54 + a2] = v * msize[a2];
    } else {
      int a2 = c - 101;
      out[O_SEM + bp*18 + a2] = v;
    }
  }
}

// ---------------------------------------------------------------------------
extern "C" void kernel_launch(void* const* d_in, const int* in_sizes, int n_in,
                              void* d_out, int out_size, void* d_ws, size_t ws_size,
                              hipStream_t stream) {
  (void)in_sizes; (void)n_in; (void)out_size; (void)ws_size;
  const float* xyz   = (const float*)d_in[0];
  const float* feats = (const float*)d_in[1];
  const float* msize = (const float*)d_in[2];
  const float* w0  = (const float*)d_in[3];
  const float* b0  = (const float*)d_in[4];
  const float* g0  = (const float*)d_in[5];
  const float* be0 = (const float*)d_in[6];
  const float* w1  = (const float*)d_in[7];
  const float* b1  = (const float*)d_in[8];
  const float* g1  = (const float*)d_in[9];
  const float* be1 = (const float*)d_in[10];
  const float* w2  = (const float*)d_in[11];
  const float* b2  = (const float*)d_in[12];
  const float* g2  = (const float*)d_in[13];
  const float* be2 = (const float*)d_in[14];
  const float* wf1  = (const float*)d_in[15];
  const float* bf1  = (const float*)d_in[16];
  const float* gf1  = (const float*)d_in[17];
  const float* bef1 = (const float*)d_in[18];
  const float* wf2  = (const float*)d_in[19];
  const float* bf2  = (const float*)d_in[20];
  const float* gf2  = (const float*)d_in[21];
  const float* bef2 = (const float*)d_in[22];
  const float* w3 = (const float*)d_in[23];
  const float* b3 = (const float*)d_in[24];

  float* out = (float*)d_out;

  // workspace layout (bytes)
  char* wsb = (char*)d_ws;
  int*            ws_idx = (int*)           (wsb + 0);          //  512 KiB
  unsigned short* fbf    = (unsigned short*)(wsb + 524288);     // 16 MiB
  float*          featws = (float*)         (wsb + 17301504);   //  4 MiB
  unsigned short* w0bt   = (unsigned short*)(wsb + 21495808);   //  72 KiB
  unsigned short* w1bt   = (unsigned short*)(wsb + 21569536);   //  32 KiB
  unsigned short* w2bt   = (unsigned short*)(wsb + 21602304);   //  32 KiB
  float*          w3p    = (float*)         (wsb + 21635072);   //  64 KiB
  float*          gb0    = (float*)         (wsb + 21700608);   //  512 B
  float*          gb1    = (float*)         (wsb + 21701120);   //  512 B
  float*          gb2    = (float*)         (wsb + 21701632);   //  512 B

  fps_kernel<<<BATCH, 64, 0, stream>>>(xyz, out + O_NX, out + O_INDS);
  bq_kernel<<<(BATCH*NPROP)/4, 256, 0, stream>>>(xyz, out + O_NX, ws_idx);
  prep_kernel<<<4096 + 338, 256, 0, stream>>>(
      feats, fbf, w0, w1, w2, w3,
      b0, g0, be0, b1, g1, be1, b2, g2, be2,
      w0bt, w1bt, w2bt, w3p, gb0, gb1, gb2);
  group_mlp_kernel<<<(BATCH*NPROP)/2, 64, 0, stream>>>(
      xyz, fbf, w0bt, w1bt, w2bt,
      g0, gb0, g1, gb1, g2, gb2,
      ws_idx, out + O_NX, featws);
  fc_head_kernel<<<(BATCH*NPROP)/32, 256, 0, stream>>>(
      featws, out + O_NX, msize,
      wf1, bf1, gf1, bef1, wf2, bf2, gf2, bef2, w3p, b3, out);
}

// Round 5
// 434.204 us; speedup vs baseline: 1.9474x; 1.0920x over previous
//
#include <hip/hip_runtime.h>

#define BATCH 32
#define NPTS  1024
#define NFEAT 256
#define NPROP 256
#define NSAMP 16

// flat output offsets (floats), in reference tuple order
#define O_OBJ    0
#define O_CENTER 16384
#define O_HS     40960
#define O_HRN    139264
#define O_HR     237568
#define O_SS     335872
#define O_SRN    483328
#define O_SR     925696
#define O_SEM    1368064
#define O_NX     1515520
#define O_INDS   1540096

typedef __attribute__((ext_vector_type(8))) short bf16x8;
typedef __attribute__((ext_vector_type(8))) unsigned short u16x8;
typedef __attribute__((ext_vector_type(16))) float f32x16;

__device__ __forceinline__ unsigned short f2bf(float f) {
  unsigned u = __builtin_bit_cast(unsigned, f);
  u += 0x7fffu + ((u >> 16) & 1u);   // RNE to bf16
  return (unsigned short)(u >> 16);
}

// single-op DPP reduction steps (validated ctrl pattern: R3 passed with it)
template<int CTRL>
__device__ __forceinline__ float dpp_maxf(float v) {
  int x = __builtin_amdgcn_update_dpp(__builtin_bit_cast(int, v),
          __builtin_bit_cast(int, v), CTRL, 0xf, 0xf, false);
  return fmaxf(v, __builtin_bit_cast(float, x));
}
template<int CTRL>
__device__ __forceinline__ int dpp_mini(int v) {
  int x = __builtin_amdgcn_update_dpp(v, v, CTRL, 0xf, 0xf, false);
  return min(v, x);
}

// ---------------------------------------------------------------------------
// Kernel 1: FPS — one wave per batch, 16 pts/lane in registers.
// Value-first: running-min update; per-lane max TREE; 6x1-op DPP max;
// equality-select min index; 6x1-op DPP min. Exact fp32, first-max tie-break.
// ---------------------------------------------------------------------------
__global__ __launch_bounds__(64) void fps_kernel(
    const float* __restrict__ xyz,
    float* __restrict__ o_nx,
    float* __restrict__ o_inds)
{
#pragma clang fp contract(off)
  __shared__ float sxyz[NPTS*3];
  __shared__ int   sInd[NPROP];

  const int b = blockIdx.x;
  const int t = threadIdx.x;              // 0..63
  const float* xb = xyz + b * NPTS * 3;
  for (int i = t; i < NPTS*3; i += 64) sxyz[i] = xb[i];
  __syncthreads();

  // slot j holds point t + 64*j
  float px[16], py[16], pz[16], dd[16];
  int idxr[16];
#pragma unroll
  for (int j = 0; j < 16; ++j) {
    int k = t + 64*j;
    px[j] = sxyz[k*3+0]; py[j] = sxyz[k*3+1]; pz[j] = sxyz[k*3+2];
    dd[j] = 1e10f;
    idxr[j] = k;
  }

  int last = 0;
  for (int it = 1; it < NPROP; ++it) {
    float lx = sxyz[last*3+0], ly = sxyz[last*3+1], lz = sxyz[last*3+2];
    // running-min update (exact: sub, mul, add, add — contraction off)
#pragma unroll
    for (int j = 0; j < 16; ++j) {
      float dx = px[j] - lx;
      float dy = py[j] - ly;
      float dz = pz[j] - lz;
      float d  = dx*dx + dy*dy + dz*dz;
      dd[j] = fminf(dd[j], d);
    }
    // per-lane max tree (depth 4)
    float m01 = fmaxf(dd[0], dd[1]),  m23 = fmaxf(dd[2], dd[3]);
    float m45 = fmaxf(dd[4], dd[5]),  m67 = fmaxf(dd[6], dd[7]);
    float m89 = fmaxf(dd[8], dd[9]),  mab = fmaxf(dd[10], dd[11]);
    float mcd = fmaxf(dd[12], dd[13]), mef = fmaxf(dd[14], dd[15]);
    float a0 = fmaxf(m01, m23), a1 = fmaxf(m45, m67);
    float a2 = fmaxf(m89, mab), a3 = fmaxf(mcd, mef);
    float m = fmaxf(fmaxf(a0, a1), fmaxf(a2, a3));
    // cross-lane max -> lane 63
    m = dpp_maxf<0x111>(m);   // row_shr:1
    m = dpp_maxf<0x112>(m);   // row_shr:2
    m = dpp_maxf<0x114>(m);   // row_shr:4
    m = dpp_maxf<0x118>(m);   // row_shr:8
    m = dpp_maxf<0x142>(m);   // row_bcast:15
    m = dpp_maxf<0x143>(m);   // row_bcast:31
    float gmax = __builtin_bit_cast(float,
        __builtin_amdgcn_readlane(__builtin_bit_cast(int, m), 63));
    // per-lane min index among slots equal to gmax (tree)
    int c[8];
#pragma unroll
    for (int j = 0; j < 8; ++j) {
      int clo = (dd[2*j]   == gmax) ? idxr[2*j]   : 0x7fffffff;
      int chi = (dd[2*j+1] == gmax) ? idxr[2*j+1] : 0x7fffffff;
      c[j] = min(clo, chi);
    }
    int c0 = min(c[0], c[1]), c1 = min(c[2], c[3]);
    int c2 = min(c[4], c[5]), c3 = min(c[6], c[7]);
    int cand = min(min(c0, c1), min(c2, c3));
    // cross-lane min-index -> lane 63
    cand = dpp_mini<0x111>(cand);
    cand = dpp_mini<0x112>(cand);
    cand = dpp_mini<0x114>(cand);
    cand = dpp_mini<0x118>(cand);
    cand = dpp_mini<0x142>(cand);
    cand = dpp_mini<0x143>(cand);
    last = __builtin_amdgcn_readlane(cand, 63);
    if (t == 0) sInd[it] = last;
  }
  if (t == 0) sInd[0] = 0;
  __syncthreads();

  for (int s = t; s < NPROP; s += 64) {
    int ind = sInd[s];
    o_inds[b*NPROP + s] = (float)ind;
    float* nx = o_nx + (b*NPROP + s)*3;
    nx[0] = sxyz[ind*3+0]; nx[1] = sxyz[ind*3+1]; nx[2] = sxyz[ind*3+2];
  }
}

// ---------------------------------------------------------------------------
// Kernel 1b: ball query — one wave per proposal (unchanged; exact).
// ---------------------------------------------------------------------------
__global__ __launch_bounds__(256) void bq_kernel(
    const float* __restrict__ xyz,
    const float* __restrict__ o_nx,
    int* __restrict__ ws_idx)
{
  const int lane = threadIdx.x & 63;
  const int wid  = threadIdx.x >> 6;
  const int bp   = blockIdx.x * 4 + wid;
  const int b    = bp >> 8;
  const float* xb = xyz + b * NPTS * 3;

  const float qx = o_nx[bp*3+0];
  const float qy = o_nx[bp*3+1];
  const float qz = o_nx[bp*3+2];

  const int k0 = lane * 16;
  unsigned mask = 0u;
#pragma unroll
  for (int j = 0; j < 16; ++j) {
    int k = k0 + j;
    float dx = __fsub_rn(qx, xb[k*3+0]);
    float dy = __fsub_rn(qy, xb[k*3+1]);
    float dz = __fsub_rn(qz, xb[k*3+2]);
    float d2 = __fadd_rn(__fadd_rn(__fmul_rn(dx,dx), __fmul_rn(dy,dy)), __fmul_rn(dz,dz));
    if (d2 < 0.09f) mask |= (1u << j);
  }
  int cnt  = __popc(mask);
  int incl = cnt;
#pragma unroll
  for (int ofs = 1; ofs < 64; ofs <<= 1) {
    int v = __shfl_up(incl, ofs);
    if (lane >= ofs) incl += v;
  }
  int start = incl - cnt;
  int total = __shfl(incl, 63);

  int fc = mask ? (k0 + __ffs(mask) - 1) : 0x7fffffff;
#pragma unroll
  for (int m = 32; m >= 1; m >>= 1) fc = min(fc, __shfl_xor(fc, m));
  int first = (total > 0) ? fc : (NPTS - 1);

  const int base = bp * NSAMP;
  int pos = start;
  unsigned mm = mask;
  while (mm && pos < NSAMP) {
    int j = __ffs(mm) - 1; mm &= mm - 1;
    ws_idx[base + pos] = k0 + j;
    ++pos;
  }
  if (lane >= total && lane < NSAMP) ws_idx[base + lane] = first;
}

// ---------------------------------------------------------------------------
// Merged prep: feats->bf16; weights -> bf16 B-layout [n][k]; gb = g*b+be.
// ---------------------------------------------------------------------------
__global__ __launch_bounds__(256) void prep_kernel(
    const float* __restrict__ feats, unsigned short* __restrict__ fbf,
    const float* __restrict__ w0, const float* __restrict__ w1,
    const float* __restrict__ w2, const float* __restrict__ w3,
    const float* __restrict__ b0, const float* __restrict__ g0, const float* __restrict__ be0,
    const float* __restrict__ b1, const float* __restrict__ g1, const float* __restrict__ be1,
    const float* __restrict__ b2, const float* __restrict__ g2, const float* __restrict__ be2,
    unsigned short* __restrict__ w0bt, unsigned short* __restrict__ w1bt,
    unsigned short* __restrict__ w2bt, float* __restrict__ w3p,
    float* __restrict__ gb0, float* __restrict__ gb1, float* __restrict__ gb2)
{
  if (blockIdx.x < 4096) {
    size_t i = ((size_t)blockIdx.x * 256 + threadIdx.x) * 8;
    float4 f0 = *(const float4*)(feats + i);
    float4 f1 = *(const float4*)(feats + i + 4);
    u16x8 o;
    o[0]=f2bf(f0.x); o[1]=f2bf(f0.y); o[2]=f2bf(f0.z); o[3]=f2bf(f0.w);
    o[4]=f2bf(f1.x); o[5]=f2bf(f1.y); o[6]=f2bf(f1.z); o[7]=f2bf(f1.w);
    *(u16x8*)(fbf + i) = o;
    return;
  }
  int id = (blockIdx.x - 4096) * 256 + threadIdx.x;
  if (id < 36864) {                       // w0bt [128][288]
    int n = id / 288, k = id - 288*n;
    float v = 0.f;
    if (k < 256) v = w0[(k+3)*128 + n];
    else if (k < 259) v = w0[(k-256)*128 + n];
    w0bt[id] = f2bf(v);
  } else if (id < 53248) {                // w1bt [128][128]
    int j = id - 36864; int n = j >> 7, k = j & 127;
    w1bt[j] = f2bf(w1[k*128 + n]);
  } else if (id < 69632) {                // w2bt [128][128]
    int j = id - 53248; int n = j >> 7, k = j & 127;
    w2bt[j] = f2bf(w2[k*128 + n]);
  } else if (id < 86016) {                // w3p [128][128] fp32, zero-padded
    int j = id - 69632; int k = j >> 7, c = j & 127;
    w3p[j] = (c < 119) ? w3[k*119 + c] : 0.f;
  } else if (id < 86144) {
    int c = id - 86016; gb0[c] = fmaf(g0[c], b0[c], be0[c]);
  } else if (id < 86272) {
    int c = id - 86144; gb1[c] = fmaf(g1[c], b1[c], be1[c]);
  } else if (id < 86400) {
    int c = id - 86272; gb2[c] = fmaf(g2[c], b2[c], be2[c]);
  }
}

// ---------------------------------------------------------------------------
// Kernel 2a: grouped MLP via 32x32x16 bf16 MFMA.
// 256-thread blocks = 4 independent waves; each wave processes 2 proposals
// with a private 8 KiB LDS act slice (fix for 1-wave-WG residency collapse:
// R4 showed Occupancy 0.86%, VALUBusy 0.3% on 64-thread grids).
// ---------------------------------------------------------------------------
__global__ __launch_bounds__(256) void group_mlp_kernel(
    const float* __restrict__ xyz,
    const unsigned short* __restrict__ fbf,
    const unsigned short* __restrict__ w0bt,
    const unsigned short* __restrict__ w1bt,
    const unsigned short* __restrict__ w2bt,
    const float* __restrict__ g0, const float* __restrict__ gb0,
    const float* __restrict__ g1, const float* __restrict__ gb1,
    const float* __restrict__ g2, const float* __restrict__ gb2,
    const int* __restrict__ ws_idx,
    const float* __restrict__ onx,
    float* __restrict__ featws)
{
  __shared__ __align__(16) unsigned short act[4*4096];   // 32 KiB (8 KiB/wave)

  const int tid  = threadIdx.x;
  const int wave = tid >> 6;
  const int lane = tid & 63;
  const int s  = lane & 31;        // A row (sample) / B-D col bits (channel)
  const int h  = lane >> 5;        // K-half
  const int n0 = s;                // channel lane for B/D
  const int gw = blockIdx.x * 4 + wave;       // global wave id, 0..4095
  const int p  = gw * 2 + (s >> 4);           // this lane's A-row proposal
  const int b  = gw >> 7;                     // batch
  const int samp = s & 15;
  unsigned short* actw = act + wave * 4096;

  const int idx = ws_idx[p*16 + samp];
  const unsigned short* arow = fbf + ((size_t)(b*NPTS + idx) << 8);

  // gxyz A-fragment for kstep 16 (k=256..258 live in h==0 lanes)
  bf16x8 agx = (bf16x8){0,0,0,0,0,0,0,0};
  if (h == 0) {
    const float* pp = xyz + (size_t)(b*NPTS + idx)*3;
    agx[0] = (short)f2bf((pp[0] - onx[p*3+0]) * (1.0f/0.3f));
    agx[1] = (short)f2bf((pp[1] - onx[p*3+1]) * (1.0f/0.3f));
    agx[2] = (short)f2bf((pp[2] - onx[p*3+2]) * (1.0f/0.3f));
  }

  f32x16 acc[4];
#pragma unroll
  for (int nt = 0; nt < 4; ++nt) acc[nt] = (f32x16)(0.f);

  // ---- layer 0: K = 259 (ksteps 0..15 feats, 16 = gxyz; all-zero kstep 17 skipped)
  for (int ks = 0; ks < 16; ++ks) {
    bf16x8 a = *(const bf16x8*)(arow + ks*16 + h*8);
    const unsigned short* wp = w0bt + (size_t)n0*288 + ks*16 + h*8;
#pragma unroll
    for (int nt = 0; nt < 4; ++nt) {
      bf16x8 bb = *(const bf16x8*)(wp + (size_t)nt*32*288);
      acc[nt] = __builtin_amdgcn_mfma_f32_32x32x16_bf16(a, bb, acc[nt], 0, 0, 0);
    }
  }
  {
    const unsigned short* wp = w0bt + (size_t)n0*288 + 256 + h*8;
#pragma unroll
    for (int nt = 0; nt < 4; ++nt) {
      bf16x8 bb = *(const bf16x8*)(wp + (size_t)nt*32*288);
      acc[nt] = __builtin_amdgcn_mfma_f32_32x32x16_bf16(agx, bb, acc[nt], 0, 0, 0);
    }
  }
  // act0 -> LDS (relu(g*x+gb)), swizzled layout
#pragma unroll
  for (int nt = 0; nt < 4; ++nt) {
    int c = nt*32 + n0;
    int gch = c >> 3;
    float gg = g0[c], gv = gb0[c];
    int base = gch*256 + (c & 7);
#pragma unroll
    for (int r = 0; r < 16; ++r) {
      int srow = (r & 3) + 8*(r >> 2) + 4*h;
      float v = fmaxf(fmaf(gg, acc[nt][r], gv), 0.f);
      actw[base + ((srow + 2*gch) & 31)*8] = f2bf(v);
    }
  }
  __syncthreads();

  // ---- layer 1: K = 128
#pragma unroll
  for (int nt = 0; nt < 4; ++nt) acc[nt] = (f32x16)(0.f);
  for (int ks = 0; ks < 8; ++ks) {
    int g = ks*2 + h;
    bf16x8 a = *(const bf16x8*)(actw + g*256 + ((s + 2*g) & 31)*8);
    const unsigned short* wp = w1bt + (size_t)n0*128 + ks*16 + h*8;
#pragma unroll
    for (int nt = 0; nt < 4; ++nt) {
      bf16x8 bb = *(const bf16x8*)(wp + (size_t)nt*32*128);
      acc[nt] = __builtin_amdgcn_mfma_f32_32x32x16_bf16(a, bb, acc[nt], 0, 0, 0);
    }
  }
  __syncthreads();
#pragma unroll
  for (int nt = 0; nt < 4; ++nt) {
    int c = nt*32 + n0;
    int gch = c >> 3;
    float gg = g1[c], gv = gb1[c];
    int base = gch*256 + (c & 7);
#pragma unroll
    for (int r = 0; r < 16; ++r) {
      int srow = (r & 3) + 8*(r >> 2) + 4*h;
      float v = fmaxf(fmaf(gg, acc[nt][r], gv), 0.f);
      actw[base + ((srow + 2*gch) & 31)*8] = f2bf(v);
    }
  }
  __syncthreads();

  // ---- layer 2: K = 128, fused maxpool over each proposal's 16 samples
#pragma unroll
  for (int nt = 0; nt < 4; ++nt) acc[nt] = (f32x16)(0.f);
  for (int ks = 0; ks < 8; ++ks) {
    int g = ks*2 + h;
    bf16x8 a = *(const bf16x8*)(actw + g*256 + ((s + 2*g) & 31)*8);
    const unsigned short* wp = w2bt + (size_t)n0*128 + ks*16 + h*8;
#pragma unroll
    for (int nt = 0; nt < 4; ++nt) {
      bf16x8 bb = *(const bf16x8*)(wp + (size_t)nt*32*128);
      acc[nt] = __builtin_amdgcn_mfma_f32_32x32x16_bf16(a, bb, acc[nt], 0, 0, 0);
    }
  }
#pragma unroll
  for (int nt = 0; nt < 4; ++nt) {
    int c = nt*32 + n0;
    float gg = g2[c], gv = gb2[c];
    float m0 = 0.f, m1 = 0.f;   // relu => max >= 0
#pragma unroll
    for (int r = 0; r < 8; ++r)
      m0 = fmaxf(m0, fmaxf(fmaf(gg, acc[nt][r], gv), 0.f));       // rows 0..15  (prop lo)
#pragma unroll
    for (int r = 8; r < 16; ++r)
      m1 = fmaxf(m1, fmaxf(fmaf(gg, acc[nt][r], gv), 0.f));       // rows 16..31 (prop hi)
    m0 = fmaxf(m0, __shfl_xor(m0, 32));
    m1 = fmaxf(m1, __shfl_xor(m1, 32));
    float vout = h ? m1 : m0;
    featws[(size_t)(gw*2 + h)*128 + c] = vout;
  }
}

// ---------------------------------------------------------------------------
// Kernel 2b: FC head batched over proposals — fp32, 32 rows/block, 256 thr.
// ---------------------------------------------------------------------------
#define FCS 132
__global__ __launch_bounds__(256) void fc_head_kernel(
    const float* __restrict__ featws,
    const float* __restrict__ onx,
    const float* __restrict__ msize,
    const float* __restrict__ wf1, const float* __restrict__ bf1,
    const float* __restrict__ gf1, const float* __restrict__ bef1,
    const float* __restrict__ wf2, const float* __restrict__ bf2,
    const float* __restrict__ gf2, const float* __restrict__ bef2,
    const float* __restrict__ w3p, const float* __restrict__ b3,
    float* __restrict__ out)
{
  __shared__ float A[32*FCS];
  __shared__ float Bb[32*FCS];
  const int t = threadIdx.x;
  const int r = t >> 3;
  const int g = t & 7;
  const int row0 = blockIdx.x * 32;

#pragma unroll
  for (int i = 0; i < 16; ++i) {
    int id = t + 256*i;
    int rr = id >> 7, cc = id & 127;
    A[rr*FCS + cc] = featws[(size_t)(row0+rr)*128 + cc];
  }
  __syncthreads();

  float acc[16];
  // ---- FC1 (relu6): A -> Bb
#pragma unroll
  for (int i = 0; i < 16; ++i) acc[i] = 0.f;
#pragma unroll 4
  for (int k = 0; k < 128; ++k) {
    float a = A[r*FCS + k];
    const float4* wv = (const float4*)(wf1 + k*128 + g*16);
    float4 v0 = wv[0], v1 = wv[1], v2 = wv[2], v3 = wv[3];
    acc[0]  = fmaf(a, v0.x, acc[0]);  acc[1]  = fmaf(a, v0.y, acc[1]);
    acc[2]  = fmaf(a, v0.z, acc[2]);  acc[3]  = fmaf(a, v0.w, acc[3]);
    acc[4]  = fmaf(a, v1.x, acc[4]);  acc[5]  = fmaf(a, v1.y, acc[5]);
    acc[6]  = fmaf(a, v1.z, acc[6]);  acc[7]  = fmaf(a, v1.w, acc[7]);
    acc[8]  = fmaf(a, v2.x, acc[8]);  acc[9]  = fmaf(a, v2.y, acc[9]);
    acc[10] = fmaf(a, v2.z, acc[10]); acc[11] = fmaf(a, v2.w, acc[11]);
    acc[12] = fmaf(a, v3.x, acc[12]); acc[13] = fmaf(a, v3.y, acc[13]);
    acc[14] = fmaf(a, v3.z, acc[14]); acc[15] = fmaf(a, v3.w, acc[15]);
  }
#pragma unroll
  for (int i = 0; i < 16; ++i) {
    int c = g*16 + i;
    Bb[r*FCS + c] = fminf(fmaxf(fmaf(gf1[c], acc[i] + bf1[c], bef1[c]), 0.f), 6.f);
  }
  __syncthreads();

  // ---- FC2 (relu6): Bb -> A
#pragma unroll
  for (int i = 0; i < 16; ++i) acc[i] = 0.f;
#pragma unroll 4
  for (int k = 0; k < 128; ++k) {
    float a = Bb[r*FCS + k];
    const float4* wv = (const float4*)(wf2 + k*128 + g*16);
    float4 v0 = wv[0], v1 = wv[1], v2 = wv[2], v3 = wv[3];
    acc[0]  = fmaf(a, v0.x, acc[0]);  acc[1]  = fmaf(a, v0.y, acc[1]);
    acc[2]  = fmaf(a, v0.z, acc[2]);  acc[3]  = fmaf(a, v0.w, acc[3]);
    acc[4]  = fmaf(a, v1.x, acc[4]);  acc[5]  = fmaf(a, v1.y, acc[5]);
    acc[6]  = fmaf(a, v1.z, acc[6]);  acc[7]  = fmaf(a, v1.w, acc[7]);
    acc[8]  = fmaf(a, v2.x, acc[8]);  acc[9]  = fmaf(a, v2.y, acc[9]);
    acc[10] = fmaf(a, v2.z, acc[10]); acc[11] = fmaf(a, v2.w, acc[11]);
    acc[12] = fmaf(a, v3.x, acc[12]); acc[13] = fmaf(a, v3.y, acc[13]);
    acc[14] = fmaf(a, v3.z, acc[14]); acc[15] = fmaf(a, v3.w, acc[15]);
  }
#pragma unroll
  for (int i = 0; i < 16; ++i) {
    int c = g*16 + i;
    A[r*FCS + c] = fminf(fmaxf(fmaf(gf2[c], acc[i] + bf2[c], bef2[c]), 0.f), 6.f);
  }
  __syncthreads();

  // ---- FC3: A -> 119 outs, scatter with transforms
#pragma unroll
  for (int i = 0; i < 16; ++i) acc[i] = 0.f;
#pragma unroll 4
  for (int k = 0; k < 128; ++k) {
    float a = A[r*FCS + k];
    const float4* wv = (const float4*)(w3p + k*128 + g*16);
    float4 v0 = wv[0], v1 = wv[1], v2 = wv[2], v3 = wv[3];
    acc[0]  = fmaf(a, v0.x, acc[0]);  acc[1]  = fmaf(a, v0.y, acc[1]);
    acc[2]  = fmaf(a, v0.z, acc[2]);  acc[3]  = fmaf(a, v0.w, acc[3]);
    acc[4]  = fmaf(a, v1.x, acc[4]);  acc[5]  = fmaf(a, v1.y, acc[5]);
    acc[6]  = fmaf(a, v1.z, acc[6]);  acc[7]  = fmaf(a, v1.w, acc[7]);
    acc[8]  = fmaf(a, v2.x, acc[8]);  acc[9]  = fmaf(a, v2.y, acc[9]);
    acc[10] = fmaf(a, v2.z, acc[10]); acc[11] = fmaf(a, v2.w, acc[11]);
    acc[12] = fmaf(a, v3.x, acc[12]); acc[13] = fmaf(a, v3.y, acc[13]);
    acc[14] = fmaf(a, v3.z, acc[14]); acc[15] = fmaf(a, v3.w, acc[15]);
  }
  const int bp = row0 + r;
  const float HRC = (float)(3.14159265359 / 12.0);
#pragma unroll
  for (int i = 0; i < 16; ++i) {
    int c = g*16 + i;
    if (c >= 119) continue;
    float v = acc[i] + b3[c];
    if (c < 3) {
      out[O_CENTER + bp*3 + c] = onx[bp*3 + c] + v;
    } else if (c < 5) {
      out[O_OBJ + bp*2 + (c-3)] = v;
    } else if (c < 17) {
      out[O_HS + bp*12 + (c-5)] = v;
    } else if (c < 35) {
      out[O_SS + bp*18 + (c-17)] = v;
    } else if (c < 47) {
      int a2 = c - 35;
      out[O_HRN + bp*12 + a2] = v;
      out[O_HR  + bp*12 + a2] = v * HRC;
    } else if (c < 101) {
      int a2 = c - 47;
      out[O_SRN + bp*54 + a2] = v;
      out[O_SR  + bp*54 + a2] = v * msize[a2];
    } else {
      int a2 = c - 101;
      out[O_SEM + bp*18 + a2] = v;
    }
  }
}

// ---------------------------------------------------------------------------
extern "C" void kernel_launch(void* const* d_in, const int* in_sizes, int n_in,
                              void* d_out, int out_size, void* d_ws, size_t ws_size,
                              hipStream_t stream) {
  (void)in_sizes; (void)n_in; (void)out_size; (void)ws_size;
  const float* xyz   = (const float*)d_in[0];
  const float* feats = (const float*)d_in[1];
  const float* msize = (const float*)d_in[2];
  const float* w0  = (const float*)d_in[3];
  const float* b0  = (const float*)d_in[4];
  const float* g0  = (const float*)d_in[5];
  const float* be0 = (const float*)d_in[6];
  const float* w1  = (const float*)d_in[7];
  const float* b1  = (const float*)d_in[8];
  const float* g1  = (const float*)d_in[9];
  const float* be1 = (const float*)d_in[10];
  const float* w2  = (const float*)d_in[11];
  const float* b2  = (const float*)d_in[12];
  const float* g2  = (const float*)d_in[13];
  const float* be2 = (const float*)d_in[14];
  const float* wf1  = (const float*)d_in[15];
  const float* bf1  = (const float*)d_in[16];
  const float* gf1  = (const float*)d_in[17];
  const float* bef1 = (const float*)d_in[18];
  const float* wf2  = (const float*)d_in[19];
  const float* bf2  = (const float*)d_in[20];
  const float* gf2  = (const float*)d_in[21];
  const float* bef2 = (const float*)d_in[22];
  const float* w3 = (const float*)d_in[23];
  const float* b3 = (const float*)d_in[24];

  float* out = (float*)d_out;

  // workspace layout (bytes)
  char* wsb = (char*)d_ws;
  int*            ws_idx = (int*)           (wsb + 0);          //  512 KiB
  unsigned short* fbf    = (unsigned short*)(wsb + 524288);     // 16 MiB
  float*          featws = (float*)         (wsb + 17301504);   //  4 MiB
  unsigned short* w0bt   = (unsigned short*)(wsb + 21495808);   //  72 KiB
  unsigned short* w1bt   = (unsigned short*)(wsb + 21569536);   //  32 KiB
  unsigned short* w2bt   = (unsigned short*)(wsb + 21602304);   //  32 KiB
  float*          w3p    = (float*)         (wsb + 21635072);   //  64 KiB
  float*          gb0    = (float*)         (wsb + 21700608);   //  512 B
  float*          gb1    = (float*)         (wsb + 21701120);   //  512 B
  float*          gb2    = (float*)         (wsb + 21701632);   //  512 B

  fps_kernel<<<BATCH, 64, 0, stream>>>(xyz, out + O_NX, out + O_INDS);
  bq_kernel<<<(BATCH*NPROP)/4, 256, 0, stream>>>(xyz, out + O_NX, ws_idx);
  prep_kernel<<<4096 + 338, 256, 0, stream>>>(
      feats, fbf, w0, w1, w2, w3,
      b0, g0, be0, b1, g1, be1, b2, g2, be2,
      w0bt, w1bt, w2bt, w3p, gb0, gb1, gb2);
  group_mlp_kernel<<<(BATCH*NPROP)/8, 256, 0, stream>>>(
      xyz, fbf, w0bt, w1bt, w2bt,
      g0, gb0, g1, gb1, g2, gb2,
      ws_idx, out + O_NX, featws);
  fc_head_kernel<<<(BATCH*NPROP)/32, 256, 0, stream>>>(
      featws, out + O_NX, msize,
      wf1, bf1, gf1, bef1, wf2, bf2, gf2, bef2, w3p, b3, out);
}